// Round 9
// baseline (289.898 us; speedup 1.0000x reference)
//
#include <hip/hip_runtime.h>
#include <cstddef>

#define NB 16384
#define TS 720    // act batch stride in halves (10 slots * 72)

typedef __attribute__((ext_vector_type(8))) _Float16 half8;
typedef __attribute__((ext_vector_type(4))) _Float16 half4;
typedef __attribute__((ext_vector_type(4))) float f32x4;
typedef __attribute__((ext_vector_type(2))) float f32x2;
typedef __attribute__((ext_vector_type(16))) float f32x16;

// ---- ws float offsets ----
#define OFF_W1T 0
#define OFF_SC1 768
#define OFF_SH1 832
#define OFF_SC2 896
#define OFF_SH2 960
#define OFF_SC3 1024
#define OFF_SH3 1088
#define OFF_PB  1152
#define OFF_PBB 1216
#define OFF_W2H 2304                   // w2 hi 10240 f, then lo 10240 f (contiguous)
#define OFF_W2L 12544
#define OFF_W3H 22784                  // w3 hi 14336 f, then lo 14336 f (contiguous)
#define OFF_W3L 37120
#define OFF_TF  51456                  // tail frags: 31744 halves = 15872 floats

// tail frag half-offsets within OFF_TF region
#define G1H 0
#define G1L 8192
#define G2H 16384
#define G2L 20480
#define H1H 24576
#define H1L 26624
#define H2H 28672
#define H2L 29184
#define COH 29696
#define COL 30720
#define TFH 31744   // total halves

// tail LDS scratch half-offsets (inside reused ah region, wave 0 only)
#define CMBH 0
#define CMBL 2176
#define T1H  4352
#define T1L  5504
#define FLH  6656
#define FLL  7808
#define RH   8960
#define RL   9600

static __device__ __forceinline__ f32x16 mfma32(half8 a, half8 b, f32x16 c) {
  return __builtin_amdgcn_mfma_f32_32x32x16_f16(a, b, c, 0, 0, 0);
}
static __device__ __forceinline__ f32x4 mfma16(half4 a, half4 b, f32x4 c) {
  return __builtin_amdgcn_mfma_f32_16x16x16f16(a, b, c, 0, 0, 0);
}
static __device__ __forceinline__ f32x4 mfma16k32(half8 a, half8 b, f32x4 c) {
  return __builtin_amdgcn_mfma_f32_16x16x32_f16(a, b, c, 0, 0, 0);
}

// ============================ prep ============================
__global__ __launch_bounds__(256) void prep_kernel(
    const float* __restrict__ conv1_w, const float* __restrict__ conv1_b,
    const float* __restrict__ conv2_w, const float* __restrict__ conv2_b,
    const float* __restrict__ conv3_w, const float* __restrict__ conv3_b,
    const float* __restrict__ bn1_g, const float* __restrict__ bn1_b,
    const float* __restrict__ bn2_g, const float* __restrict__ bn2_b,
    const float* __restrict__ bn3_g, const float* __restrict__ bn3_b,
    const float* __restrict__ proj_w, const float* __restrict__ proj_b,
    const float* __restrict__ A, const float* __restrict__ Bm,
    const float* __restrict__ Cm, const float* __restrict__ out_w,
    const float* __restrict__ g1_w, const float* __restrict__ g2_w,
    const float* __restrict__ h1_w, const float* __restrict__ h2_w,
    float* __restrict__ ws)
{
  int tid = blockIdx.x * blockDim.x + threadIdx.x;
  int nt = gridDim.x * blockDim.x;
  const float s = rsqrtf(1.0f + 1e-5f);

  for (int i = tid; i < 64*12; i += nt) {
    int o = i & 63, rk = i >> 6;
    ws[OFF_W1T + i] = conv1_w[o*12 + rk];
  }
  for (int o = tid; o < 64; o += nt) {
    float s1 = bn1_g[o]*s, s2 = bn2_g[o]*s, s3 = bn3_g[o]*s;
    ws[OFF_SC1+o] = s1; ws[OFF_SH1+o] = s1*conv1_b[o] + bn1_b[o];
    ws[OFF_SC2+o] = s2; ws[OFF_SH2+o] = s2*conv2_b[o] + bn2_b[o];
    ws[OFF_SC3+o] = s3; ws[OFF_SH3+o] = s3*conv3_b[o] + bn3_b[o];
  }
  // conv2 A-fragments (32x32x16), hi/lo split
  {
    _Float16* w2h = (_Float16*)(ws + OFF_W2H);
    _Float16* w2l = (_Float16*)(ws + OFF_W2L);
    for (int i = tid; i < 20*2*64; i += nt) {
      int lane = i & 63, ot = (i >> 6) & 1, sk = i >> 7;
      int tap = sk >> 2, ic0 = (sk & 3)*16 + (lane >> 5)*8;
      int o = ot*32 + (lane & 31);
      #pragma unroll
      for (int j = 0; j < 8; ++j) {
        float w = conv2_w[o*320 + (ic0 + j)*5 + tap];
        _Float16 hi = (_Float16)w;
        w2h[(size_t)i*8 + j] = hi;
        w2l[(size_t)i*8 + j] = (_Float16)(w - (float)hi);
      }
    }
  }
  {
    _Float16* w3h = (_Float16*)(ws + OFF_W3H);
    _Float16* w3l = (_Float16*)(ws + OFF_W3L);
    for (int i = tid; i < 28*2*64; i += nt) {
      int lane = i & 63, ot = (i >> 6) & 1, sk = i >> 7;
      int tap = sk >> 2, ic0 = (sk & 3)*16 + (lane >> 5)*8;
      int o = ot*32 + (lane & 31);
      #pragma unroll
      for (int j = 0; j < 8; ++j) {
        float w = conv3_w[o*448 + (ic0 + j)*7 + tap];
        _Float16 hi = (_Float16)w;
        w3h[(size_t)i*8 + j] = hi;
        w3l[(size_t)i*8 + j] = (_Float16)(w - (float)hi);
      }
    }
  }
  // PB[c][j], PBB[j]
  for (int i = tid; i < 64; i += nt) {
    int c = i >> 4, j = i & 15;
    float acc = 0.f;
    for (int m = 0; m < 64; ++m) acc += proj_w[c*64+m]*Bm[m*16+j];
    ws[OFF_PB + i] = acc;
  }
  for (int j = tid; j < 16; j += nt) {
    float acc = 0.f;
    for (int m = 0; m < 64; ++m) acc += proj_b[m]*Bm[m*16+j];
    ws[OFF_PBB + j] = acc;
  }

  // ---- tail MFMA fragments (hi/lo) ----
  _Float16* tf = (_Float16*)(ws + OFF_TF);
  for (int i = tid; i < 16*64; i += nt) {
    int l = i & 63, f = i >> 6, mt = f >> 2, ks = f & 3;
    int o = mt*16 + (l & 15), kb = ks*32 + (l >> 4)*8;
    #pragma unroll
    for (int j = 0; j < 8; ++j) {
      float w = g1_w[(size_t)(kb + j)*64 + o];
      _Float16 hi = (_Float16)w;
      tf[G1H + (size_t)i*8 + j] = hi;
      tf[G1L + (size_t)i*8 + j] = (_Float16)(w - (float)hi);
    }
  }
  for (int i = tid; i < 8*64; i += nt) {
    int l = i & 63, f = i >> 6, mt = f >> 1, ks = f & 1;
    int o = mt*16 + (l & 15), kb = ks*32 + (l >> 4)*8;
    #pragma unroll
    for (int j = 0; j < 8; ++j) {
      float w = g2_w[(size_t)(kb + j)*64 + o];
      _Float16 hi = (_Float16)w;
      tf[G2H + (size_t)i*8 + j] = hi;
      tf[G2L + (size_t)i*8 + j] = (_Float16)(w - (float)hi);
    }
  }
  for (int i = tid; i < 4*64; i += nt) {
    int l = i & 63, f = i >> 6, mt = f >> 1, ks = f & 1;
    int hx = mt*16 + (l & 15), kb = ks*32 + (l >> 4)*8;
    #pragma unroll
    for (int j = 0; j < 8; ++j) {
      float w = h1_w[(size_t)(kb + j)*32 + hx];
      _Float16 hi = (_Float16)w;
      tf[H1H + (size_t)i*8 + j] = hi;
      tf[H1L + (size_t)i*8 + j] = (_Float16)(w - (float)hi);
    }
  }
  for (int i = tid; i < 64; i += nt) {
    int l = i, m = l & 15, kb = (l >> 4)*8;
    #pragma unroll
    for (int j = 0; j < 8; ++j) {
      float w = (m < 3) ? h2_w[(size_t)(kb + j)*3 + m] : 0.f;
      _Float16 hi = (_Float16)w;
      tf[H2H + (size_t)i*8 + j] = hi;
      tf[H2L + (size_t)i*8 + j] = (_Float16)(w - (float)hi);
    }
  }
  for (int i = tid; i < 4*64; i += nt) {
    int l = i & 63, mt = i >> 6;
    int o = mt*16 + (l & 15), kb = (l >> 4)*4;
    #pragma unroll
    for (int j = 0; j < 4; ++j) {
      float acc = 0.f;
      for (int m = 0; m < 64; ++m) acc += Cm[(kb + j)*64 + m]*out_w[m*64 + o];
      _Float16 hi = (_Float16)acc;
      tf[COH + (size_t)i*4 + j] = hi;
      tf[COL + (size_t)i*4 + j] = (_Float16)(acc - (float)hi);
    }
  }
}

// ============================ fully fused conv1+conv2+conv3 + RNN + tail ============================
// One block = 16 batches end-to-end. Waves 0-3: R4-verified conv (4 batches/
// wave, wave-private LDS). conv3 epi writes sf to a SEPARATE 4KB LDS buffer
// (no aliasing with live act rows). One __syncthreads; waves 1-3 exit; wave 0
// runs the 16-batch RNN (h stays in registers: RNN lane layout == tail h
// layout) then the tail chain, with wa scratch reusing the dead ah region and
// tail weight frags read directly from global (L2/L3-hot).
// Rationale: tail's parallelism quantum is 16 batches/wave -> 1024 waves =
// 1 wave/SIMD standalone (latency-bound, can't self-hide). Fused, it hides
// under co-resident blocks' conv (30% MFMA / 38% VALU leaves issue slots).
// Also deletes the tail launch+boundary and the sf/h global roundtrips.
// LDS 50,176 B -> still 3 blocks/CU (3x50176 < 160KB).
__global__ __launch_bounds__(256, 3) void conv123_kernel(
    const float* __restrict__ x, const float* __restrict__ wsr,
    const float* __restrict__ A,
    const float* __restrict__ g1_b, const float* __restrict__ g2_b,
    const float* __restrict__ h1_b, const float* __restrict__ h2_b,
    const float* __restrict__ out_b, float* __restrict__ out)
{
  __shared__ __align__(16) _Float16 ah[16][TS], al[16][TS];
  __shared__ __align__(16) float sfl[16][64];

  const int tid = threadIdx.x;
  const int lane = tid & 63;
  const int wid = tid >> 6;

  const int n = lane & 15;
  const int nc = (n < 10) ? n : 9;
  const int kh8 = (lane >> 5) * 8;
  const int rq = 4 * (lane >> 5);
  const int lbA = 4*wid + ((lane >> 4) & 1);   // pair A: batches 4w, 4w+1
  const int lbB = lbA + 2;                     // pair B: batches 4w+2, 4w+3
  const half8 z8 = {};
  const size_t B0g = (size_t)blockIdx.x * 16;

  // conv1 for this wave's 4 batches (writes wave-private LDS rows)
  {
    const float sc1 = wsr[OFF_SC1 + lane], sh1 = wsr[OFF_SH1 + lane];
    #pragma unroll
    for (int bb = 0; bb < 4; ++bb) {
      const int lb = 4*wid + bb;
      const size_t gb = B0g + lb;
      float xv[4][12];
      #pragma unroll
      for (int c = 0; c < 4; ++c) { xv[c][0] = 0.f; xv[c][11] = 0.f; }
      #pragma unroll
      for (int tt = 0; tt < 10; ++tt) {
        const f32x4 xt = *(const f32x4*)(x + gb*400 + (90 + tt)*4);
        #pragma unroll
        for (int c = 0; c < 4; ++c) xv[c][1 + tt] = xt[c];
      }
      float a1[10];
      #pragma unroll
      for (int t = 0; t < 10; ++t) a1[t] = 0.f;
      #pragma unroll
      for (int c = 0; c < 4; ++c)
        #pragma unroll
        for (int k = 0; k < 3; ++k) {
          const float wv = wsr[OFF_W1T + (c*3 + k)*64 + lane];
          #pragma unroll
          for (int t = 0; t < 10; ++t) a1[t] += wv * xv[c][t + k];
        }
      #pragma unroll
      for (int t = 0; t < 10; ++t) {
        float v = sc1*a1[t] + sh1;
        v = v > 0.f ? v : 0.f;
        _Float16 hi = (_Float16)v;
        ah[lb][t*72 + lane] = hi;
        al[lb][t*72 + lane] = (_Float16)(v - (float)hi);
      }
    }
  }

  const _Float16* bhpA = &ah[lbA][0];
  const _Float16* blpA = &al[lbA][0];
  const _Float16* bhpB = &ah[lbB][0];
  const _Float16* blpB = &al[lbB][0];
  const _Float16* w2h = (const _Float16*)(wsr + OFF_W2H);
  const _Float16* w2l = (const _Float16*)(wsr + OFF_W2L);
  const _Float16* w3h = (const _Float16*)(wsr + OFF_W3H);
  const _Float16* w3l = (const _Float16*)(wsr + OFF_W3L);
  const int lw8 = lane*8;

  // conv2: both otiles x both batch-pairs; weights loaded once per sk
  {
    f32x16 a0A, a1A, a0B, a1B;
    #pragma unroll
    for (int r = 0; r < 16; ++r) { a0A[r] = 0.f; a1A[r] = 0.f; a0B[r] = 0.f; a1B[r] = 0.f; }
    #pragma unroll
    for (int sk = 0; sk < 20; ++sk) {
      const int tap = sk >> 2, icb = (sk & 3)*16;
      const int t = nc + tap - 2;
      const int tc = t < 0 ? 0 : (t > 9 ? 9 : t);
      const bool valid = (t >= 0) & (t <= 9);
      const int off = tc*72 + icb + kh8;
      half8 bhA = *(const half8*)(bhpA + off);
      half8 blA = *(const half8*)(blpA + off);
      half8 bhB = *(const half8*)(bhpB + off);
      half8 blB = *(const half8*)(blpB + off);
      bhA = valid ? bhA : z8;
      blA = valid ? blA : z8;
      bhB = valid ? bhB : z8;
      blB = valid ? blB : z8;
      const half8 wh0 = *(const half8*)(w2h + (size_t)(sk*2 + 0)*512 + lw8);
      const half8 wh1 = *(const half8*)(w2h + (size_t)(sk*2 + 1)*512 + lw8);
      const half8 wl0 = *(const half8*)(w2l + (size_t)(sk*2 + 0)*512 + lw8);
      const half8 wl1 = *(const half8*)(w2l + (size_t)(sk*2 + 1)*512 + lw8);
      a0A = mfma32(wh0, bhA, a0A);
      a0A = mfma32(wh0, blA, a0A);
      a0A = mfma32(wl0, bhA, a0A);
      a1A = mfma32(wh1, bhA, a1A);
      a1A = mfma32(wh1, blA, a1A);
      a1A = mfma32(wl1, bhA, a1A);
      a0B = mfma32(wh0, bhB, a0B);
      a0B = mfma32(wh0, blB, a0B);
      a0B = mfma32(wl0, bhB, a0B);
      a1B = mfma32(wh1, bhB, a1B);
      a1B = mfma32(wh1, blB, a1B);
      a1B = mfma32(wl1, bhB, a1B);
    }
    // epi2: act2 written over act1 rows (wave-private; per-wave DS ops are
    // in-order and the writes data-depend on all reads via the accumulators)
    if (n < 10) {
      auto epi = [&](const f32x16& ac, int ot, int lb) {
        #pragma unroll
        for (int q = 0; q < 4; ++q) {
          const int rowb = 8*q + rq + ot*32;
          const f32x4 sc = *(const f32x4*)(wsr + OFF_SC2 + rowb);
          const f32x4 sh = *(const f32x4*)(wsr + OFF_SH2 + rowb);
          half4 h4, l4;
          #pragma unroll
          for (int r = 0; r < 4; ++r) {
            float v = sc[r]*ac[4*q + r] + sh[r];
            v = v > 0.f ? v : 0.f;
            _Float16 hi = (_Float16)v;
            h4[r] = hi;
            l4[r] = (_Float16)(v - (float)hi);
          }
          *(half4*)(&ah[lb][n*72 + rowb]) = h4;
          *(half4*)(&al[lb][n*72 + rowb]) = l4;
        }
      };
      epi(a0A, 0, lbA);
      epi(a1A, 1, lbA);
      epi(a0B, 0, lbB);
      epi(a1B, 1, lbB);
    }
  }

  // conv3: both otiles x both batch-pairs; weights loaded once per sk
  {
    f32x16 b0A, b1A, b0B, b1B;
    #pragma unroll
    for (int r = 0; r < 16; ++r) { b0A[r] = 0.f; b1A[r] = 0.f; b0B[r] = 0.f; b1B[r] = 0.f; }
    #pragma unroll
    for (int sk = 0; sk < 28; ++sk) {
      const int tap = sk >> 2, icb = (sk & 3)*16;
      const int t = nc + tap - 3;
      const int tc = t < 0 ? 0 : (t > 9 ? 9 : t);
      const bool valid = (t >= 0) & (t <= 9);
      const int off = tc*72 + icb + kh8;
      half8 bhA = *(const half8*)(bhpA + off);
      half8 blA = *(const half8*)(blpA + off);
      half8 bhB = *(const half8*)(bhpB + off);
      half8 blB = *(const half8*)(blpB + off);
      bhA = valid ? bhA : z8;
      blA = valid ? blA : z8;
      bhB = valid ? bhB : z8;
      blB = valid ? blB : z8;
      const half8 wh0 = *(const half8*)(w3h + (size_t)(sk*2 + 0)*512 + lw8);
      const half8 wh1 = *(const half8*)(w3h + (size_t)(sk*2 + 1)*512 + lw8);
      const half8 wl0 = *(const half8*)(w3l + (size_t)(sk*2 + 0)*512 + lw8);
      const half8 wl1 = *(const half8*)(w3l + (size_t)(sk*2 + 1)*512 + lw8);
      b0A = mfma32(wh0, bhA, b0A);
      b0A = mfma32(wh0, blA, b0A);
      b0A = mfma32(wl0, bhA, b0A);
      b1A = mfma32(wh1, bhA, b1A);
      b1A = mfma32(wh1, blA, b1A);
      b1A = mfma32(wl1, bhA, b1A);
      b0B = mfma32(wh0, bhB, b0B);
      b0B = mfma32(wh0, blB, b0B);
      b0B = mfma32(wl0, bhB, b0B);
      b1B = mfma32(wh1, bhB, b1B);
      b1B = mfma32(wh1, blB, b1B);
      b1B = mfma32(wl1, bhB, b1B);
    }
    auto epi = [&](const f32x16& ac, int ot, int lb) {
      #pragma unroll
      for (int q = 0; q < 4; ++q) {
        const int rowb = 8*q + rq + ot*32;
        const f32x4 sc = *(const f32x4*)(wsr + OFF_SC3 + rowb);
        const f32x4 sh = *(const f32x4*)(wsr + OFF_SH3 + rowb);
        f32x4 v;
        #pragma unroll
        for (int r = 0; r < 4; ++r) {
          float t2 = sc[r]*ac[4*q + r] + sh[r];
          t2 = t2 > 0.f ? t2 : 0.f;
          v[r] = (n < 10) ? t2 : 0.f;
        }
        #pragma unroll
        for (int r = 0; r < 4; ++r) {
          v[r] += __shfl_xor(v[r], 1, 16);
          v[r] += __shfl_xor(v[r], 2, 16);
          v[r] += __shfl_xor(v[r], 4, 16);
          v[r] += __shfl_xor(v[r], 8, 16);
        }
        if (n == 0)
          *(f32x4*)(&sfl[lb][rowb]) = v * 0.1f;
      }
    };
    epi(b0A, 0, lbA);
    epi(b1A, 1, lbA);
    epi(b0B, 0, lbB);
    epi(b1B, 1, lbB);
  }

  __syncthreads();
  if (wid != 0) return;

  // ---------------- wave 0: RNN (16 batches, h stays in registers) ----------------
  const int colb = lane & 15;
  const int q = lane >> 4;
  f32x4 hf;
  {
    const size_t b = B0g + colb;
    const f32x4 av = *(const f32x4*)(A + (size_t)colb*16 + q*4);
    half4 Ahi, Alo;
    #pragma unroll
    for (int j = 0; j < 4; ++j) {
      _Float16 hi = (_Float16)av[j];
      Ahi[j] = hi;
      Alo[j] = (_Float16)(av[j] - (float)hi);
    }
    f32x4 pb0 = *(const f32x4*)(wsr + OFF_PB + 0*16 + q*4);
    f32x4 pb1 = *(const f32x4*)(wsr + OFF_PB + 1*16 + q*4);
    f32x4 pb2 = *(const f32x4*)(wsr + OFF_PB + 2*16 + q*4);
    f32x4 pb3 = *(const f32x4*)(wsr + OFF_PB + 3*16 + q*4);
    f32x4 pbb = *(const f32x4*)(wsr + OFF_PBB + q*4);

    const float* xb = x + b*400;
    half4 hh = {}, hl = {};
    #pragma unroll 2
    for (int t = 0; t < 100; ++t) {
      const f32x4 xv = *(const f32x4*)(xb + t*4);
      f32x4 U;
      #pragma unroll
      for (int r = 0; r < 4; ++r)
        U[r] = pbb[r] + xv[0]*pb0[r] + xv[1]*pb1[r] + xv[2]*pb2[r] + xv[3]*pb3[r];
      f32x4 u = mfma16(Alo, hh, U);
      u = mfma16(Ahi, hl, u);
      u = mfma16(Ahi, hh, u);
      #pragma unroll
      for (int r = 0; r < 4; ++r) {
        float e = __expf(2.f*u[r]);
        float hn = 1.f - 2.f/(e + 1.f);
        hf[r] = hn;
        _Float16 hi = (_Float16)hn;
        hh[r] = hi;
        hl[r] = (_Float16)(hn - (float)hi);
      }
    }
  }

  // ---------------- wave 0: tail (16 batches; wa scratch = dead ah region) ----------------
  {
    const _Float16* tfg = (const _Float16*)(wsr + OFF_TF);
    _Float16* wa = &ah[0][0];

    half4 hh, hl;
    #pragma unroll
    for (int j = 0; j < 4; ++j) {
      _Float16 hi = (_Float16)hf[j];
      hh[j] = hi;
      hl[j] = (_Float16)(hf[j] - (float)hi);
    }
    f32x4 lc[4];
    #pragma unroll
    for (int mt = 0; mt < 4; ++mt) {
      lc[mt] = *(const f32x4*)(out_b + mt*16 + q*4);
      const half4 ca = *(const half4*)(tfg + COH + (size_t)(mt*64 + lane)*4);
      const half4 cl = *(const half4*)(tfg + COL + (size_t)(mt*64 + lane)*4);
      lc[mt] = mfma16(cl, hh, lc[mt]);
      lc[mt] = mfma16(ca, hl, lc[mt]);
      lc[mt] = mfma16(ca, hh, lc[mt]);
    }
    f32x4 sfv[4];
    #pragma unroll
    for (int mt = 0; mt < 4; ++mt) {
      sfv[mt] = *(const f32x4*)(&sfl[n][mt*16 + q*4]);
      half4 sh4, sl4, lh4, ll4;
      #pragma unroll
      for (int r = 0; r < 4; ++r) {
        _Float16 hi = (_Float16)sfv[mt][r];
        sh4[r] = hi; sl4[r] = (_Float16)(sfv[mt][r] - (float)hi);
        _Float16 hi2 = (_Float16)lc[mt][r];
        lh4[r] = hi2; ll4[r] = (_Float16)(lc[mt][r] - (float)hi2);
      }
      *(half4*)(wa + CMBH + n*136 + mt*16 + q*4) = sh4;
      *(half4*)(wa + CMBL + n*136 + mt*16 + q*4) = sl4;
      *(half4*)(wa + CMBH + n*136 + 64 + mt*16 + q*4) = lh4;
      *(half4*)(wa + CMBL + n*136 + 64 + mt*16 + q*4) = ll4;
    }
    f32x4 u1[4];
    #pragma unroll
    for (int mt = 0; mt < 4; ++mt) u1[mt] = *(const f32x4*)(g1_b + mt*16 + q*4);
    #pragma unroll
    for (int ks = 0; ks < 4; ++ks) {
      const half8 bh = *(const half8*)(wa + CMBH + n*136 + ks*32 + q*8);
      const half8 bl = *(const half8*)(wa + CMBL + n*136 + ks*32 + q*8);
      #pragma unroll
      for (int mt = 0; mt < 4; ++mt) {
        const half8 fa = *(const half8*)(tfg + G1H + (size_t)((mt*4 + ks)*64 + lane)*8);
        const half8 fl = *(const half8*)(tfg + G1L + (size_t)((mt*4 + ks)*64 + lane)*8);
        u1[mt] = mfma16k32(fl, bh, u1[mt]);
        u1[mt] = mfma16k32(fa, bl, u1[mt]);
        u1[mt] = mfma16k32(fa, bh, u1[mt]);
      }
    }
    #pragma unroll
    for (int mt = 0; mt < 4; ++mt) {
      half4 th4, tl4;
      #pragma unroll
      for (int r = 0; r < 4; ++r) {
        float e = __expf(2.f*u1[mt][r]);
        float t1 = 1.f - 2.f/(e + 1.f);
        _Float16 hi = (_Float16)t1;
        th4[r] = hi; tl4[r] = (_Float16)(t1 - (float)hi);
      }
      *(half4*)(wa + T1H + n*72 + mt*16 + q*4) = th4;
      *(half4*)(wa + T1L + n*72 + mt*16 + q*4) = tl4;
    }
    f32x4 u2[4];
    #pragma unroll
    for (int mt = 0; mt < 4; ++mt) u2[mt] = *(const f32x4*)(g2_b + mt*16 + q*4);
    #pragma unroll
    for (int ks = 0; ks < 2; ++ks) {
      const half8 bh = *(const half8*)(wa + T1H + n*72 + ks*32 + q*8);
      const half8 bl = *(const half8*)(wa + T1L + n*72 + ks*32 + q*8);
      #pragma unroll
      for (int mt = 0; mt < 4; ++mt) {
        const half8 fa = *(const half8*)(tfg + G2H + (size_t)((mt*2 + ks)*64 + lane)*8);
        const half8 fl = *(const half8*)(tfg + G2L + (size_t)((mt*2 + ks)*64 + lane)*8);
        u2[mt] = mfma16k32(fl, bh, u2[mt]);
        u2[mt] = mfma16k32(fa, bl, u2[mt]);
        u2[mt] = mfma16k32(fa, bh, u2[mt]);
      }
    }
    #pragma unroll
    for (int mt = 0; mt < 4; ++mt) {
      half4 fh4, fl4;
      #pragma unroll
      for (int r = 0; r < 4; ++r) {
        float gate = 1.f/(1.f + __expf(-u2[mt][r]));
        float f = sfv[mt][r] * gate;
        _Float16 hi = (_Float16)f;
        fh4[r] = hi; fl4[r] = (_Float16)(f - (float)hi);
      }
      *(half4*)(wa + FLH + n*72 + mt*16 + q*4) = fh4;
      *(half4*)(wa + FLL + n*72 + mt*16 + q*4) = fl4;
    }
    f32x4 u3[2];
    #pragma unroll
    for (int mt = 0; mt < 2; ++mt) u3[mt] = *(const f32x4*)(h1_b + mt*16 + q*4);
    #pragma unroll
    for (int ks = 0; ks < 2; ++ks) {
      const half8 bh = *(const half8*)(wa + FLH + n*72 + ks*32 + q*8);
      const half8 bl = *(const half8*)(wa + FLL + n*72 + ks*32 + q*8);
      #pragma unroll
      for (int mt = 0; mt < 2; ++mt) {
        const half8 fa = *(const half8*)(tfg + H1H + (size_t)((mt*2 + ks)*64 + lane)*8);
        const half8 fl = *(const half8*)(tfg + H1L + (size_t)((mt*2 + ks)*64 + lane)*8);
        u3[mt] = mfma16k32(fl, bh, u3[mt]);
        u3[mt] = mfma16k32(fa, bl, u3[mt]);
        u3[mt] = mfma16k32(fa, bh, u3[mt]);
      }
    }
    #pragma unroll
    for (int mt = 0; mt < 2; ++mt) {
      half4 rh4, rl4;
      #pragma unroll
      for (int r = 0; r < 4; ++r) {
        float v = fmaxf(u3[mt][r], 0.f);
        _Float16 hi = (_Float16)v;
        rh4[r] = hi; rl4[r] = (_Float16)(v - (float)hi);
      }
      *(half4*)(wa + RH + n*40 + mt*16 + q*4) = rh4;
      *(half4*)(wa + RL + n*40 + mt*16 + q*4) = rl4;
    }
    {
      f32x4 u4;
      if (q == 0) { u4[0] = h2_b[0]; u4[1] = h2_b[1]; u4[2] = h2_b[2]; u4[3] = 0.f; }
      else { u4[0] = 0.f; u4[1] = 0.f; u4[2] = 0.f; u4[3] = 0.f; }
      const half8 bh = *(const half8*)(wa + RH + n*40 + q*8);
      const half8 bl = *(const half8*)(wa + RL + n*40 + q*8);
      const half8 fa = *(const half8*)(tfg + H2H + (size_t)lane*8);
      const half8 fl = *(const half8*)(tfg + H2L + (size_t)lane*8);
      u4 = mfma16k32(fl, bh, u4);
      u4 = mfma16k32(fa, bl, u4);
      u4 = mfma16k32(fa, bh, u4);
      if (q == 0) {
        out[(size_t)(B0g + n)*3 + 0] = u4[0];
        out[(size_t)(B0g + n)*3 + 1] = u4[1];
        out[(size_t)(B0g + n)*3 + 2] = u4[2];
      }
    }
  }
}

// ============================ launch ============================
extern "C" void kernel_launch(void* const* d_in, const int* in_sizes, int n_in,
                              void* d_out, int out_size, void* d_ws, size_t ws_size,
                              hipStream_t stream) {
  const float* x       = (const float*)d_in[0];
  const float* conv1_w = (const float*)d_in[1];
  const float* conv1_b = (const float*)d_in[2];
  const float* conv2_w = (const float*)d_in[3];
  const float* conv2_b = (const float*)d_in[4];
  const float* conv3_w = (const float*)d_in[5];
  const float* conv3_b = (const float*)d_in[6];
  const float* bn1_g   = (const float*)d_in[7];
  const float* bn1_b   = (const float*)d_in[8];
  const float* bn2_g   = (const float*)d_in[9];
  const float* bn2_b   = (const float*)d_in[10];
  const float* bn3_g   = (const float*)d_in[11];
  const float* bn3_b   = (const float*)d_in[12];
  const float* proj_w  = (const float*)d_in[13];
  const float* proj_b  = (const float*)d_in[14];
  const float* A       = (const float*)d_in[15];
  const float* Bm      = (const float*)d_in[16];
  const float* Cm      = (const float*)d_in[17];
  const float* out_w   = (const float*)d_in[18];
  const float* out_b   = (const float*)d_in[19];
  const float* g1_w    = (const float*)d_in[20];
  const float* g1_b    = (const float*)d_in[21];
  const float* g2_w    = (const float*)d_in[22];
  const float* g2_b    = (const float*)d_in[23];
  const float* h1_w    = (const float*)d_in[24];
  const float* h1_b    = (const float*)d_in[25];
  const float* h2_w    = (const float*)d_in[26];
  const float* h2_b    = (const float*)d_in[27];
  float* ws = (float*)d_ws;
  float* out = (float*)d_out;

  prep_kernel<<<64, 256, 0, stream>>>(conv1_w, conv1_b, conv2_w, conv2_b,
      conv3_w, conv3_b, bn1_g, bn1_b, bn2_g, bn2_b, bn3_g, bn3_b,
      proj_w, proj_b, A, Bm, Cm, out_w, g1_w, g2_w, h1_w, h2_w, ws);

  conv123_kernel<<<NB/16, 256, 0, stream>>>(x, ws, A,
      g1_b, g2_b, h1_b, h2_b, out_b, out);
}

// Round 11
// 240.275 us; speedup vs baseline: 1.2065x; 1.2065x over previous
//
#include <hip/hip_runtime.h>
#include <cstddef>

#define NB 16384
#define NRNN (NB/64)   // 256 leading rnn blocks (4 waves x 16 batches each)

typedef __attribute__((ext_vector_type(8))) _Float16 half8;
typedef __attribute__((ext_vector_type(4))) _Float16 half4;
typedef __attribute__((ext_vector_type(4))) float f32x4;
typedef __attribute__((ext_vector_type(2))) float f32x2;
typedef __attribute__((ext_vector_type(16))) float f32x16;

// ---- ws float offsets ----
#define OFF_W1T 0
#define OFF_SC1 768
#define OFF_SH1 832
#define OFF_SC2 896
#define OFF_SH2 960
#define OFF_SC3 1024
#define OFF_SH3 1088
#define OFF_PB  1152
#define OFF_PBB 1216
#define OFF_W2H 2304                   // w2 hi 10240 f, then lo 10240 f (contiguous)
#define OFF_W2L 12544
#define OFF_W3H 22784                  // w3 hi 14336 f, then lo 14336 f (contiguous)
#define OFF_W3L 37120
#define OFF_SF  51456                  // NB*64
#define OFF_H   (51456 + NB*64)        // NB*16 -> ends 1362176
#define OFF_TF  1362176                // tail frags: 31744 halves = 15872 floats

// tail frag half-offsets within OFF_TF region
#define G1H 0
#define G1L 8192
#define G2H 16384
#define G2L 20480
#define H1H 24576
#define H1L 26624
#define H2H 28672
#define H2L 29184
#define COH 29696
#define COL 30720
#define TFH 31744   // total halves

static __device__ __forceinline__ f32x16 mfma32(half8 a, half8 b, f32x16 c) {
  return __builtin_amdgcn_mfma_f32_32x32x16_f16(a, b, c, 0, 0, 0);
}
static __device__ __forceinline__ f32x4 mfma16(half4 a, half4 b, f32x4 c) {
  return __builtin_amdgcn_mfma_f32_16x16x16f16(a, b, c, 0, 0, 0);
}
static __device__ __forceinline__ f32x4 mfma16k32(half8 a, half8 b, f32x4 c) {
  return __builtin_amdgcn_mfma_f32_16x16x32_f16(a, b, c, 0, 0, 0);
}

// ============================ prep ============================
__global__ __launch_bounds__(256) void prep_kernel(
    const float* __restrict__ conv1_w, const float* __restrict__ conv1_b,
    const float* __restrict__ conv2_w, const float* __restrict__ conv2_b,
    const float* __restrict__ conv3_w, const float* __restrict__ conv3_b,
    const float* __restrict__ bn1_g, const float* __restrict__ bn1_b,
    const float* __restrict__ bn2_g, const float* __restrict__ bn2_b,
    const float* __restrict__ bn3_g, const float* __restrict__ bn3_b,
    const float* __restrict__ proj_w, const float* __restrict__ proj_b,
    const float* __restrict__ A, const float* __restrict__ Bm,
    const float* __restrict__ Cm, const float* __restrict__ out_w,
    const float* __restrict__ g1_w, const float* __restrict__ g2_w,
    const float* __restrict__ h1_w, const float* __restrict__ h2_w,
    float* __restrict__ ws)
{
  int tid = blockIdx.x * blockDim.x + threadIdx.x;
  int nt = gridDim.x * blockDim.x;
  const float s = rsqrtf(1.0f + 1e-5f);

  for (int i = tid; i < 64*12; i += nt) {
    int o = i & 63, rk = i >> 6;
    ws[OFF_W1T + i] = conv1_w[o*12 + rk];
  }
  for (int o = tid; o < 64; o += nt) {
    float s1 = bn1_g[o]*s, s2 = bn2_g[o]*s, s3 = bn3_g[o]*s;
    ws[OFF_SC1+o] = s1; ws[OFF_SH1+o] = s1*conv1_b[o] + bn1_b[o];
    ws[OFF_SC2+o] = s2; ws[OFF_SH2+o] = s2*conv2_b[o] + bn2_b[o];
    ws[OFF_SC3+o] = s3; ws[OFF_SH3+o] = s3*conv3_b[o] + bn3_b[o];
  }
  // conv2 A-fragments (32x32x16), hi/lo split
  {
    _Float16* w2h = (_Float16*)(ws + OFF_W2H);
    _Float16* w2l = (_Float16*)(ws + OFF_W2L);
    for (int i = tid; i < 20*2*64; i += nt) {
      int lane = i & 63, ot = (i >> 6) & 1, sk = i >> 7;
      int tap = sk >> 2, ic0 = (sk & 3)*16 + (lane >> 5)*8;
      int o = ot*32 + (lane & 31);
      #pragma unroll
      for (int j = 0; j < 8; ++j) {
        float w = conv2_w[o*320 + (ic0 + j)*5 + tap];
        _Float16 hi = (_Float16)w;
        w2h[(size_t)i*8 + j] = hi;
        w2l[(size_t)i*8 + j] = (_Float16)(w - (float)hi);
      }
    }
  }
  {
    _Float16* w3h = (_Float16*)(ws + OFF_W3H);
    _Float16* w3l = (_Float16*)(ws + OFF_W3L);
    for (int i = tid; i < 28*2*64; i += nt) {
      int lane = i & 63, ot = (i >> 6) & 1, sk = i >> 7;
      int tap = sk >> 2, ic0 = (sk & 3)*16 + (lane >> 5)*8;
      int o = ot*32 + (lane & 31);
      #pragma unroll
      for (int j = 0; j < 8; ++j) {
        float w = conv3_w[o*448 + (ic0 + j)*7 + tap];
        _Float16 hi = (_Float16)w;
        w3h[(size_t)i*8 + j] = hi;
        w3l[(size_t)i*8 + j] = (_Float16)(w - (float)hi);
      }
    }
  }
  // PB[c][j], PBB[j]
  for (int i = tid; i < 64; i += nt) {
    int c = i >> 4, j = i & 15;
    float acc = 0.f;
    for (int m = 0; m < 64; ++m) acc += proj_w[c*64+m]*Bm[m*16+j];
    ws[OFF_PB + i] = acc;
  }
  for (int j = tid; j < 16; j += nt) {
    float acc = 0.f;
    for (int m = 0; m < 64; ++m) acc += proj_b[m]*Bm[m*16+j];
    ws[OFF_PBB + j] = acc;
  }

  // ---- tail MFMA fragments (hi/lo) ----
  _Float16* tf = (_Float16*)(ws + OFF_TF);
  for (int i = tid; i < 16*64; i += nt) {
    int l = i & 63, f = i >> 6, mt = f >> 2, ks = f & 3;
    int o = mt*16 + (l & 15), kb = ks*32 + (l >> 4)*8;
    #pragma unroll
    for (int j = 0; j < 8; ++j) {
      float w = g1_w[(size_t)(kb + j)*64 + o];
      _Float16 hi = (_Float16)w;
      tf[G1H + (size_t)i*8 + j] = hi;
      tf[G1L + (size_t)i*8 + j] = (_Float16)(w - (float)hi);
    }
  }
  for (int i = tid; i < 8*64; i += nt) {
    int l = i & 63, f = i >> 6, mt = f >> 1, ks = f & 1;
    int o = mt*16 + (l & 15), kb = ks*32 + (l >> 4)*8;
    #pragma unroll
    for (int j = 0; j < 8; ++j) {
      float w = g2_w[(size_t)(kb + j)*64 + o];
      _Float16 hi = (_Float16)w;
      tf[G2H + (size_t)i*8 + j] = hi;
      tf[G2L + (size_t)i*8 + j] = (_Float16)(w - (float)hi);
    }
  }
  for (int i = tid; i < 4*64; i += nt) {
    int l = i & 63, f = i >> 6, mt = f >> 1, ks = f & 1;
    int hx = mt*16 + (l & 15), kb = ks*32 + (l >> 4)*8;
    #pragma unroll
    for (int j = 0; j < 8; ++j) {
      float w = h1_w[(size_t)(kb + j)*32 + hx];
      _Float16 hi = (_Float16)w;
      tf[H1H + (size_t)i*8 + j] = hi;
      tf[H1L + (size_t)i*8 + j] = (_Float16)(w - (float)hi);
    }
  }
  for (int i = tid; i < 64; i += nt) {
    int l = i, m = l & 15, kb = (l >> 4)*8;
    #pragma unroll
    for (int j = 0; j < 8; ++j) {
      float w = (m < 3) ? h2_w[(size_t)(kb + j)*3 + m] : 0.f;
      _Float16 hi = (_Float16)w;
      tf[H2H + (size_t)i*8 + j] = hi;
      tf[H2L + (size_t)i*8 + j] = (_Float16)(w - (float)hi);
    }
  }
  for (int i = tid; i < 4*64; i += nt) {
    int l = i & 63, mt = i >> 6;
    int o = mt*16 + (l & 15), kb = (l >> 4)*4;
    #pragma unroll
    for (int j = 0; j < 4; ++j) {
      float acc = 0.f;
      for (int m = 0; m < 64; ++m) acc += Cm[(kb + j)*64 + m]*out_w[m*64 + o];
      _Float16 hi = (_Float16)acc;
      tf[COH + (size_t)i*4 + j] = hi;
      tf[COL + (size_t)i*4 + j] = (_Float16)(acc - (float)hi);
    }
  }
}

// ============================ conv1+conv2+conv3 (packed columns) + leading RNN ============================
// R10 (resubmit; R10 bench died on container infra, kernel re-audited clean).
// Time-axis packing: B-columns are col = b*10 + t (16 batches x 10 slots
// = exactly 160 = 5 full 32-col MFMA tiles, 100% valid) instead of R4's
// 2 batches x 16 slots (10 valid -> 62.5%). Per conv block: MFMAs 2304->1440
// (x0.625), act LDS reads x0.625, no n-masking. Block = 320 thr (5 waves),
// 1 tile/wave -> accumulators 64->32 AGPRs (spill headroom; R6/R7 trap
// avoided). Acts LDS rows b*10+t with stride 72 (R4's proven bank pattern);
// wave ownership changes between stages -> 5 cheap __syncthreads.
// Mean-over-t crosses tile boundaries -> float overlay (stride 68) + 1024-elem
// reduction. RNN stays in leading blocks; tail stays R4's staged kernel.
__global__ __launch_bounds__(320, 4) void conv123_kernel(
    const float* __restrict__ x, const float* __restrict__ wsr,
    const float* __restrict__ A, float* __restrict__ hout,
    float* __restrict__ sfp)
{
  __shared__ __align__(16) _Float16 acts[2][160][72];   // 46,080 B

  const int tid = threadIdx.x;
  const int lane = tid & 63;
  const int wid = tid >> 6;

  if (blockIdx.x < NRNN) {
    // ---------------- RNN (leading blocks, waves 0-3 x 16 batches) ----------------
    if (wid >= 4) return;
    const int colb = lane & 15;
    const int q = lane >> 4;
    const size_t b = ((size_t)blockIdx.x*4 + wid)*16 + colb;

    const f32x4 av = *(const f32x4*)(A + (size_t)colb*16 + q*4);
    half4 Ahi, Alo;
    #pragma unroll
    for (int j = 0; j < 4; ++j) {
      _Float16 hi = (_Float16)av[j];
      Ahi[j] = hi;
      Alo[j] = (_Float16)(av[j] - (float)hi);
    }
    f32x4 pb0 = *(const f32x4*)(wsr + OFF_PB + 0*16 + q*4);
    f32x4 pb1 = *(const f32x4*)(wsr + OFF_PB + 1*16 + q*4);
    f32x4 pb2 = *(const f32x4*)(wsr + OFF_PB + 2*16 + q*4);
    f32x4 pb3 = *(const f32x4*)(wsr + OFF_PB + 3*16 + q*4);
    f32x4 pbb = *(const f32x4*)(wsr + OFF_PBB + q*4);

    const float* xb = x + b*400;
    half4 hh = {}, hl = {};
    f32x4 hf;
    #pragma unroll 2
    for (int t = 0; t < 100; ++t) {
      const f32x4 xv = *(const f32x4*)(xb + t*4);
      f32x4 U;
      #pragma unroll
      for (int r = 0; r < 4; ++r)
        U[r] = pbb[r] + xv[0]*pb0[r] + xv[1]*pb1[r] + xv[2]*pb2[r] + xv[3]*pb3[r];
      f32x4 u = mfma16(Alo, hh, U);
      u = mfma16(Ahi, hl, u);
      u = mfma16(Ahi, hh, u);
      #pragma unroll
      for (int r = 0; r < 4; ++r) {
        float e = __expf(2.f*u[r]);
        float hn = 1.f - 2.f/(e + 1.f);
        hf[r] = hn;
        _Float16 hi = (_Float16)hn;
        hh[r] = hi;
        hl[r] = (_Float16)(hn - (float)hi);
      }
    }
    *(f32x4*)(hout + b*16 + q*4) = hf;
    return;
  }

  // ---------------- conv path ----------------
  const size_t B0g = (size_t)(blockIdx.x - NRNN) * 16;

  // conv1: waves 0-3, 4 batches each; rows b*10+t
  if (wid < 4) {
    const float sc1 = wsr[OFF_SC1 + lane], sh1 = wsr[OFF_SH1 + lane];
    #pragma unroll
    for (int bb = 0; bb < 4; ++bb) {
      const int lb = 4*wid + bb;
      const size_t gb = B0g + lb;
      float xv[4][12];
      #pragma unroll
      for (int c = 0; c < 4; ++c) { xv[c][0] = 0.f; xv[c][11] = 0.f; }
      #pragma unroll
      for (int tt = 0; tt < 10; ++tt) {
        const f32x4 xt = *(const f32x4*)(x + gb*400 + (90 + tt)*4);
        #pragma unroll
        for (int c = 0; c < 4; ++c) xv[c][1 + tt] = xt[c];
      }
      float a1[10];
      #pragma unroll
      for (int t = 0; t < 10; ++t) a1[t] = 0.f;
      #pragma unroll
      for (int c = 0; c < 4; ++c)
        #pragma unroll
        for (int k = 0; k < 3; ++k) {
          const float wv = wsr[OFF_W1T + (c*3 + k)*64 + lane];
          #pragma unroll
          for (int t = 0; t < 10; ++t) a1[t] += wv * xv[c][t + k];
        }
      #pragma unroll
      for (int t = 0; t < 10; ++t) {
        float v = sc1*a1[t] + sh1;
        v = v > 0.f ? v : 0.f;
        _Float16 hi = (_Float16)v;
        acts[0][lb*10 + t][lane] = hi;
        acts[1][lb*10 + t][lane] = (_Float16)(v - (float)hi);
      }
    }
  }
  __syncthreads();

  // per-lane packed-column mapping
  const int col = wid*32 + (lane & 31);      // 0..159
  const int b = col / 10;
  const int tq = col - b*10;
  const int rowbase = b*10;
  const int kh8 = (lane >> 5) * 8;
  const int rq = 4 * (lane >> 5);
  const half8 z8 = {};
  const _Float16* abase = &acts[0][0][0];
  const _Float16* lbase = &acts[1][0][0];
  const _Float16* w2h = (const _Float16*)(wsr + OFF_W2H);
  const _Float16* w2l = (const _Float16*)(wsr + OFF_W2L);
  const _Float16* w3h = (const _Float16*)(wsr + OFF_W3H);
  const _Float16* w3l = (const _Float16*)(wsr + OFF_W3L);
  const int lw8 = lane*8;

  // conv2: 1 col-tile per wave, both otiles
  f32x16 acc0, acc1;
  {
    #pragma unroll
    for (int r = 0; r < 16; ++r) { acc0[r] = 0.f; acc1[r] = 0.f; }
    #pragma unroll
    for (int sk = 0; sk < 20; ++sk) {
      const int tap = sk >> 2, icb = (sk & 3)*16;
      const int t = tq + tap - 2;
      const int tc = t < 0 ? 0 : (t > 9 ? 9 : t);
      const bool valid = (t >= 0) & (t <= 9);
      const int off = (rowbase + tc)*72 + icb + kh8;
      half8 bh = *(const half8*)(abase + off);
      half8 bl = *(const half8*)(lbase + off);
      bh = valid ? bh : z8;
      bl = valid ? bl : z8;
      const half8 wh0 = *(const half8*)(w2h + (size_t)(sk*2 + 0)*512 + lw8);
      const half8 wh1 = *(const half8*)(w2h + (size_t)(sk*2 + 1)*512 + lw8);
      const half8 wl0 = *(const half8*)(w2l + (size_t)(sk*2 + 0)*512 + lw8);
      const half8 wl1 = *(const half8*)(w2l + (size_t)(sk*2 + 1)*512 + lw8);
      acc0 = mfma32(wh0, bh, acc0);
      acc0 = mfma32(wh0, bl, acc0);
      acc0 = mfma32(wl0, bh, acc0);
      acc1 = mfma32(wh1, bh, acc1);
      acc1 = mfma32(wh1, bl, acc1);
      acc1 = mfma32(wl1, bh, acc1);
    }
  }
  __syncthreads();   // all conv2 reads complete before act2 overwrites act1

  // epi2: act2 -> same LDS rows (all 160 cols valid, every lane writes)
  {
    auto epi = [&](const f32x16& ac, int ot) {
      #pragma unroll
      for (int q = 0; q < 4; ++q) {
        const int rowc = 8*q + rq + ot*32;
        const f32x4 sc = *(const f32x4*)(wsr + OFF_SC2 + rowc);
        const f32x4 sh = *(const f32x4*)(wsr + OFF_SH2 + rowc);
        half4 h4, l4;
        #pragma unroll
        for (int r = 0; r < 4; ++r) {
          float v = sc[r]*ac[4*q + r] + sh[r];
          v = v > 0.f ? v : 0.f;
          _Float16 hi = (_Float16)v;
          h4[r] = hi;
          l4[r] = (_Float16)(v - (float)hi);
        }
        *(half4*)(&acts[0][rowbase + tq][rowc]) = h4;
        *(half4*)(&acts[1][rowbase + tq][rowc]) = l4;
      }
    };
    epi(acc0, 0);
    epi(acc1, 1);
  }
  __syncthreads();   // act2 visible to all waves

  // conv3: 1 col-tile per wave, both otiles
  {
    #pragma unroll
    for (int r = 0; r < 16; ++r) { acc0[r] = 0.f; acc1[r] = 0.f; }
    #pragma unroll
    for (int sk = 0; sk < 28; ++sk) {
      const int tap = sk >> 2, icb = (sk & 3)*16;
      const int t = tq + tap - 3;
      const int tc = t < 0 ? 0 : (t > 9 ? 9 : t);
      const bool valid = (t >= 0) & (t <= 9);
      const int off = (rowbase + tc)*72 + icb + kh8;
      half8 bh = *(const half8*)(abase + off);
      half8 bl = *(const half8*)(lbase + off);
      bh = valid ? bh : z8;
      bl = valid ? bl : z8;
      const half8 wh0 = *(const half8*)(w3h + (size_t)(sk*2 + 0)*512 + lw8);
      const half8 wh1 = *(const half8*)(w3h + (size_t)(sk*2 + 1)*512 + lw8);
      const half8 wl0 = *(const half8*)(w3l + (size_t)(sk*2 + 0)*512 + lw8);
      const half8 wl1 = *(const half8*)(w3l + (size_t)(sk*2 + 1)*512 + lw8);
      acc0 = mfma32(wh0, bh, acc0);
      acc0 = mfma32(wh0, bl, acc0);
      acc0 = mfma32(wl0, bh, acc0);
      acc1 = mfma32(wh1, bh, acc1);
      acc1 = mfma32(wh1, bl, acc1);
      acc1 = mfma32(wl1, bh, acc1);
    }
  }
  __syncthreads();   // all conv3 reads complete before float overlay overwrites

  // epi3: relu'd floats to overlay av[160][68] (43,520 B <= 46,080 B region)
  {
    float* av = (float*)&acts[0][0][0];
    auto epi = [&](const f32x16& ac, int ot) {
      #pragma unroll
      for (int q = 0; q < 4; ++q) {
        const int rowc = 8*q + rq + ot*32;
        const f32x4 sc = *(const f32x4*)(wsr + OFF_SC3 + rowc);
        const f32x4 sh = *(const f32x4*)(wsr + OFF_SH3 + rowc);
        f32x4 v;
        #pragma unroll
        for (int r = 0; r < 4; ++r) {
          float t2 = sc[r]*ac[4*q + r] + sh[r];
          v[r] = t2 > 0.f ? t2 : 0.f;
        }
        *(f32x4*)(av + (rowbase + tq)*68 + rowc) = v;
      }
    };
    epi(acc0, 0);
    epi(acc1, 1);
  }
  __syncthreads();

  // mean over t: 1024 (b,ch) pairs over 320 threads -> sfp
  {
    const float* av = (const float*)&acts[0][0][0];
    for (int i = tid; i < 1024; i += 320) {
      const int bb = i >> 6, ch = i & 63;
      float s = 0.f;
      #pragma unroll
      for (int t = 0; t < 10; ++t) s += av[(bb*10 + t)*68 + ch];
      sfp[(B0g + bb)*64 + ch] = 0.1f * s;
    }
  }
}

// ============================ tail (MFMA, 16 batches/wave) — R4 verified ============================
#define CMBH 0
#define CMBL 2176
#define T1H  4352
#define T1L  5504
#define FLH  6656
#define FLL  7808
#define RH   8960
#define RL   9600
__global__ __launch_bounds__(256) void tail_kernel(
    const float* __restrict__ wsr,
    const float* __restrict__ g1_b, const float* __restrict__ g2_b,
    const float* __restrict__ h1_b, const float* __restrict__ h2_b,
    const float* __restrict__ out_b, float* __restrict__ out)
{
  __shared__ __align__(16) _Float16 sWF[TFH];
  __shared__ __align__(16) _Float16 sAct[4*10240];

  const int tid = threadIdx.x;
  const int lane = tid & 63;
  const int wid = tid >> 6;
  const int n = lane & 15;
  const int q = lane >> 4;
  const int B0 = blockIdx.x*64 + wid*16;

  {
    const f32x4* src = (const f32x4*)(wsr + OFF_TF);
    f32x4* dst = (f32x4*)sWF;
    for (int i = tid; i < TFH/8; i += 256) dst[i] = src[i];
  }
  __syncthreads();

  _Float16* wa = sAct + wid*10240;
  const float* sf = wsr + OFF_SF;
  const float* hws = wsr + OFF_H;

  const f32x4 hv = *(const f32x4*)(hws + (size_t)(B0 + n)*16 + q*4);
  half4 hh, hl;
  #pragma unroll
  for (int j = 0; j < 4; ++j) {
    _Float16 hi = (_Float16)hv[j];
    hh[j] = hi;
    hl[j] = (_Float16)(hv[j] - (float)hi);
  }
  f32x4 lc[4];
  #pragma unroll
  for (int mt = 0; mt < 4; ++mt) {
    lc[mt] = *(const f32x4*)(out_b + mt*16 + q*4);
    const half4 ah = *(const half4*)(sWF + COH + (size_t)(mt*64 + lane)*4);
    const half4 al = *(const half4*)(sWF + COL + (size_t)(mt*64 + lane)*4);
    lc[mt] = mfma16(al, hh, lc[mt]);
    lc[mt] = mfma16(ah, hl, lc[mt]);
    lc[mt] = mfma16(ah, hh, lc[mt]);
  }
  f32x4 sfv[4];
  #pragma unroll
  for (int mt = 0; mt < 4; ++mt) {
    sfv[mt] = *(const f32x4*)(sf + (size_t)(B0 + n)*64 + mt*16 + q*4);
    half4 sh4, sl4, lh4, ll4;
    #pragma unroll
    for (int r = 0; r < 4; ++r) {
      _Float16 hi = (_Float16)sfv[mt][r];
      sh4[r] = hi; sl4[r] = (_Float16)(sfv[mt][r] - (float)hi);
      _Float16 hi2 = (_Float16)lc[mt][r];
      lh4[r] = hi2; ll4[r] = (_Float16)(lc[mt][r] - (float)hi2);
    }
    *(half4*)(wa + CMBH + n*136 + mt*16 + q*4) = sh4;
    *(half4*)(wa + CMBL + n*136 + mt*16 + q*4) = sl4;
    *(half4*)(wa + CMBH + n*136 + 64 + mt*16 + q*4) = lh4;
    *(half4*)(wa + CMBL + n*136 + 64 + mt*16 + q*4) = ll4;
  }
  f32x4 u1[4];
  #pragma unroll
  for (int mt = 0; mt < 4; ++mt) u1[mt] = *(const f32x4*)(g1_b + mt*16 + q*4);
  #pragma unroll
  for (int ks = 0; ks < 4; ++ks) {
    const half8 bh = *(const half8*)(wa + CMBH + n*136 + ks*32 + q*8);
    const half8 bl = *(const half8*)(wa + CMBL + n*136 + ks*32 + q*8);
    #pragma unroll
    for (int mt = 0; mt < 4; ++mt) {
      const half8 ah = *(const half8*)(sWF + G1H + (size_t)((mt*4 + ks)*64 + lane)*8);
      const half8 al = *(const half8*)(sWF + G1L + (size_t)((mt*4 + ks)*64 + lane)*8);
      u1[mt] = mfma16k32(al, bh, u1[mt]);
      u1[mt] = mfma16k32(ah, bl, u1[mt]);
      u1[mt] = mfma16k32(ah, bh, u1[mt]);
    }
  }
  #pragma unroll
  for (int mt = 0; mt < 4; ++mt) {
    half4 th4, tl4;
    #pragma unroll
    for (int r = 0; r < 4; ++r) {
      float e = __expf(2.f*u1[mt][r]);
      float t1 = 1.f - 2.f/(e + 1.f);
      _Float16 hi = (_Float16)t1;
      th4[r] = hi; tl4[r] = (_Float16)(t1 - (float)hi);
    }
    *(half4*)(wa + T1H + n*72 + mt*16 + q*4) = th4;
    *(half4*)(wa + T1L + n*72 + mt*16 + q*4) = tl4;
  }
  f32x4 u2[4];
  #pragma unroll
  for (int mt = 0; mt < 4; ++mt) u2[mt] = *(const f32x4*)(g2_b + mt*16 + q*4);
  #pragma unroll
  for (int ks = 0; ks < 2; ++ks) {
    const half8 bh = *(const half8*)(wa + T1H + n*72 + ks*32 + q*8);
    const half8 bl = *(const half8*)(wa + T1L + n*72 + ks*32 + q*8);
    #pragma unroll
    for (int mt = 0; mt < 4; ++mt) {
      const half8 ah = *(const half8*)(sWF + G2H + (size_t)((mt*2 + ks)*64 + lane)*8);
      const half8 al = *(const half8*)(sWF + G2L + (size_t)((mt*2 + ks)*64 + lane)*8);
      u2[mt] = mfma16k32(al, bh, u2[mt]);
      u2[mt] = mfma16k32(ah, bl, u2[mt]);
      u2[mt] = mfma16k32(ah, bh, u2[mt]);
    }
  }
  #pragma unroll
  for (int mt = 0; mt < 4; ++mt) {
    half4 fh4, fl4;
    #pragma unroll
    for (int r = 0; r < 4; ++r) {
      float gate = 1.f/(1.f + __expf(-u2[mt][r]));
      float f = sfv[mt][r] * gate;
      _Float16 hi = (_Float16)f;
      fh4[r] = hi; fl4[r] = (_Float16)(f - (float)hi);
    }
    *(half4*)(wa + FLH + n*72 + mt*16 + q*4) = fh4;
    *(half4*)(wa + FLL + n*72 + mt*16 + q*4) = fl4;
  }
  f32x4 u3[2];
  #pragma unroll
  for (int mt = 0; mt < 2; ++mt) u3[mt] = *(const f32x4*)(h1_b + mt*16 + q*4);
  #pragma unroll
  for (int ks = 0; ks < 2; ++ks) {
    const half8 bh = *(const half8*)(wa + FLH + n*72 + ks*32 + q*8);
    const half8 bl = *(const half8*)(wa + FLL + n*72 + ks*32 + q*8);
    #pragma unroll
    for (int mt = 0; mt < 2; ++mt) {
      const half8 ah = *(const half8*)(sWF + H1H + (size_t)((mt*2 + ks)*64 + lane)*8);
      const half8 al = *(const half8*)(sWF + H1L + (size_t)((mt*2 + ks)*64 + lane)*8);
      u3[mt] = mfma16k32(al, bh, u3[mt]);
      u3[mt] = mfma16k32(ah, bl, u3[mt]);
      u3[mt] = mfma16k32(ah, bh, u3[mt]);
    }
  }
  #pragma unroll
  for (int mt = 0; mt < 2; ++mt) {
    half4 rh4, rl4;
    #pragma unroll
    for (int r = 0; r < 4; ++r) {
      float v = fmaxf(u3[mt][r], 0.f);
      _Float16 hi = (_Float16)v;
      rh4[r] = hi; rl4[r] = (_Float16)(v - (float)hi);
    }
    *(half4*)(wa + RH + n*40 + mt*16 + q*4) = rh4;
    *(half4*)(wa + RL + n*40 + mt*16 + q*4) = rl4;
  }
  {
    f32x4 u4;
    if (q == 0) { u4[0] = h2_b[0]; u4[1] = h2_b[1]; u4[2] = h2_b[2]; u4[3] = 0.f; }
    else { u4[0] = 0.f; u4[1] = 0.f; u4[2] = 0.f; u4[3] = 0.f; }
    const half8 bh = *(const half8*)(wa + RH + n*40 + q*8);
    const half8 bl = *(const half8*)(wa + RL + n*40 + q*8);
    const half8 ah = *(const half8*)(sWF + H2H + (size_t)lane*8);
    const half8 al = *(const half8*)(sWF + H2L + (size_t)lane*8);
    u4 = mfma16k32(al, bh, u4);
    u4 = mfma16k32(ah, bl, u4);
    u4 = mfma16k32(ah, bh, u4);
    if (q == 0) {
      out[(size_t)(B0 + n)*3 + 0] = u4[0];
      out[(size_t)(B0 + n)*3 + 1] = u4[1];
      out[(size_t)(B0 + n)*3 + 2] = u4[2];
    }
  }
}

// ============================ launch ============================
extern "C" void kernel_launch(void* const* d_in, const int* in_sizes, int n_in,
                              void* d_out, int out_size, void* d_ws, size_t ws_size,
                              hipStream_t stream) {
  const float* x       = (const float*)d_in[0];
  const float* conv1_w = (const float*)d_in[1];
  const float* conv1_b = (const float*)d_in[2];
  const float* conv2_w = (const float*)d_in[3];
  const float* conv2_b = (const float*)d_in[4];
  const float* conv3_w = (const float*)d_in[5];
  const float* conv3_b = (const float*)d_in[6];
  const float* bn1_g   = (const float*)d_in[7];
  const float* bn1_b   = (const float*)d_in[8];
  const float* bn2_g   = (const float*)d_in[9];
  const float* bn2_b   = (const float*)d_in[10];
  const float* bn3_g   = (const float*)d_in[11];
  const float* bn3_b   = (const float*)d_in[12];
  const float* proj_w  = (const float*)d_in[13];
  const float* proj_b  = (const float*)d_in[14];
  const float* A       = (const float*)d_in[15];
  const float* Bm      = (const float*)d_in[16];
  const float* Cm      = (const float*)d_in[17];
  const float* out_w   = (const float*)d_in[18];
  const float* out_b   = (const float*)d_in[19];
  const float* g1_w    = (const float*)d_in[20];
  const float* g1_b    = (const float*)d_in[21];
  const float* g2_w    = (const float*)d_in[22];
  const float* g2_b    = (const float*)d_in[23];
  const float* h1_w    = (const float*)d_in[24];
  const float* h1_b    = (const float*)d_in[25];
  const float* h2_w    = (const float*)d_in[26];
  const float* h2_b    = (const float*)d_in[27];
  float* ws = (float*)d_ws;
  float* out = (float*)d_out;

  prep_kernel<<<64, 256, 0, stream>>>(conv1_w, conv1_b, conv2_w, conv2_b,
      conv3_w, conv3_b, bn1_g, bn1_b, bn2_g, bn2_b, bn3_g, bn3_b,
      proj_w, proj_b, A, Bm, Cm, out_w, g1_w, g2_w, h1_w, h2_w, ws);

  conv123_kernel<<<NRNN + NB/16, 320, 0, stream>>>(x, ws, A, ws + OFF_H,
      ws + OFF_SF);

  tail_kernel<<<NB/64, 256, 0, stream>>>(ws, g1_b, g2_b, h1_b, h2_b, out_b, out);
}

// Round 12
// 232.982 us; speedup vs baseline: 1.2443x; 1.0313x over previous
//
#include <hip/hip_runtime.h>
#include <cstddef>

#define NB 16384
#define NRNN (NB/64)   // 256 leading rnn blocks (4 waves x 16 batches each)

typedef __attribute__((ext_vector_type(8))) _Float16 half8;
typedef __attribute__((ext_vector_type(4))) _Float16 half4;
typedef __attribute__((ext_vector_type(4))) float f32x4;
typedef __attribute__((ext_vector_type(2))) float f32x2;
typedef __attribute__((ext_vector_type(16))) float f32x16;

// ---- ws float offsets ----
#define OFF_W1T 0
#define OFF_SC1 768
#define OFF_SH1 832
#define OFF_SC2 896
#define OFF_SH2 960
#define OFF_SC3 1024
#define OFF_SH3 1088
#define OFF_PB  1152
#define OFF_PBB 1216
#define OFF_W2H 2304                   // w2 hi 10240 f, then lo 10240 f (contiguous)
#define OFF_W2L 12544
#define OFF_W3H 22784                  // w3 hi 14336 f, then lo 14336 f (contiguous)
#define OFF_W3L 37120
#define OFF_SF  51456                  // NB*64
#define OFF_H   (51456 + NB*64)        // NB*16 -> ends 1362176
#define OFF_TF  1362176                // tail frags: 31744 halves = 15872 floats

// tail frag half-offsets within OFF_TF region
#define G1H 0
#define G1L 8192
#define G2H 16384
#define G2L 20480
#define H1H 24576
#define H1L 26624
#define H2H 28672
#define H2L 29184
#define COH 29696
#define COL 30720
#define TFH 31744   // total halves

static __device__ __forceinline__ f32x16 mfma32(half8 a, half8 b, f32x16 c) {
  return __builtin_amdgcn_mfma_f32_32x32x16_f16(a, b, c, 0, 0, 0);
}
static __device__ __forceinline__ f32x4 mfma16(half4 a, half4 b, f32x4 c) {
  return __builtin_amdgcn_mfma_f32_16x16x16f16(a, b, c, 0, 0, 0);
}
static __device__ __forceinline__ f32x4 mfma16k32(half8 a, half8 b, f32x4 c) {
  return __builtin_amdgcn_mfma_f32_16x16x32_f16(a, b, c, 0, 0, 0);
}

// ============================ prep ============================
__global__ __launch_bounds__(256) void prep_kernel(
    const float* __restrict__ conv1_w, const float* __restrict__ conv1_b,
    const float* __restrict__ conv2_w, const float* __restrict__ conv2_b,
    const float* __restrict__ conv3_w, const float* __restrict__ conv3_b,
    const float* __restrict__ bn1_g, const float* __restrict__ bn1_b,
    const float* __restrict__ bn2_g, const float* __restrict__ bn2_b,
    const float* __restrict__ bn3_g, const float* __restrict__ bn3_b,
    const float* __restrict__ proj_w, const float* __restrict__ proj_b,
    const float* __restrict__ A, const float* __restrict__ Bm,
    const float* __restrict__ Cm, const float* __restrict__ out_w,
    const float* __restrict__ g1_w, const float* __restrict__ g2_w,
    const float* __restrict__ h1_w, const float* __restrict__ h2_w,
    float* __restrict__ ws)
{
  int tid = blockIdx.x * blockDim.x + threadIdx.x;
  int nt = gridDim.x * blockDim.x;
  const float s = rsqrtf(1.0f + 1e-5f);

  for (int i = tid; i < 64*12; i += nt) {
    int o = i & 63, rk = i >> 6;
    ws[OFF_W1T + i] = conv1_w[o*12 + rk];
  }
  for (int o = tid; o < 64; o += nt) {
    float s1 = bn1_g[o]*s, s2 = bn2_g[o]*s, s3 = bn3_g[o]*s;
    ws[OFF_SC1+o] = s1; ws[OFF_SH1+o] = s1*conv1_b[o] + bn1_b[o];
    ws[OFF_SC2+o] = s2; ws[OFF_SH2+o] = s2*conv2_b[o] + bn2_b[o];
    ws[OFF_SC3+o] = s3; ws[OFF_SH3+o] = s3*conv3_b[o] + bn3_b[o];
  }
  // conv2 A-fragments (32x32x16), hi/lo split
  {
    _Float16* w2h = (_Float16*)(ws + OFF_W2H);
    _Float16* w2l = (_Float16*)(ws + OFF_W2L);
    for (int i = tid; i < 20*2*64; i += nt) {
      int lane = i & 63, ot = (i >> 6) & 1, sk = i >> 7;
      int tap = sk >> 2, ic0 = (sk & 3)*16 + (lane >> 5)*8;
      int o = ot*32 + (lane & 31);
      #pragma unroll
      for (int j = 0; j < 8; ++j) {
        float w = conv2_w[o*320 + (ic0 + j)*5 + tap];
        _Float16 hi = (_Float16)w;
        w2h[(size_t)i*8 + j] = hi;
        w2l[(size_t)i*8 + j] = (_Float16)(w - (float)hi);
      }
    }
  }
  {
    _Float16* w3h = (_Float16*)(ws + OFF_W3H);
    _Float16* w3l = (_Float16*)(ws + OFF_W3L);
    for (int i = tid; i < 28*2*64; i += nt) {
      int lane = i & 63, ot = (i >> 6) & 1, sk = i >> 7;
      int tap = sk >> 2, ic0 = (sk & 3)*16 + (lane >> 5)*8;
      int o = ot*32 + (lane & 31);
      #pragma unroll
      for (int j = 0; j < 8; ++j) {
        float w = conv3_w[o*448 + (ic0 + j)*7 + tap];
        _Float16 hi = (_Float16)w;
        w3h[(size_t)i*8 + j] = hi;
        w3l[(size_t)i*8 + j] = (_Float16)(w - (float)hi);
      }
    }
  }
  // PB[c][j], PBB[j]
  for (int i = tid; i < 64; i += nt) {
    int c = i >> 4, j = i & 15;
    float acc = 0.f;
    for (int m = 0; m < 64; ++m) acc += proj_w[c*64+m]*Bm[m*16+j];
    ws[OFF_PB + i] = acc;
  }
  for (int j = tid; j < 16; j += nt) {
    float acc = 0.f;
    for (int m = 0; m < 64; ++m) acc += proj_b[m]*Bm[m*16+j];
    ws[OFF_PBB + j] = acc;
  }

  // ---- tail MFMA fragments (hi/lo) ----
  _Float16* tf = (_Float16*)(ws + OFF_TF);
  for (int i = tid; i < 16*64; i += nt) {
    int l = i & 63, f = i >> 6, mt = f >> 2, ks = f & 3;
    int o = mt*16 + (l & 15), kb = ks*32 + (l >> 4)*8;
    #pragma unroll
    for (int j = 0; j < 8; ++j) {
      float w = g1_w[(size_t)(kb + j)*64 + o];
      _Float16 hi = (_Float16)w;
      tf[G1H + (size_t)i*8 + j] = hi;
      tf[G1L + (size_t)i*8 + j] = (_Float16)(w - (float)hi);
    }
  }
  for (int i = tid; i < 8*64; i += nt) {
    int l = i & 63, f = i >> 6, mt = f >> 1, ks = f & 1;
    int o = mt*16 + (l & 15), kb = ks*32 + (l >> 4)*8;
    #pragma unroll
    for (int j = 0; j < 8; ++j) {
      float w = g2_w[(size_t)(kb + j)*64 + o];
      _Float16 hi = (_Float16)w;
      tf[G2H + (size_t)i*8 + j] = hi;
      tf[G2L + (size_t)i*8 + j] = (_Float16)(w - (float)hi);
    }
  }
  for (int i = tid; i < 4*64; i += nt) {
    int l = i & 63, f = i >> 6, mt = f >> 1, ks = f & 1;
    int hx = mt*16 + (l & 15), kb = ks*32 + (l >> 4)*8;
    #pragma unroll
    for (int j = 0; j < 8; ++j) {
      float w = h1_w[(size_t)(kb + j)*32 + hx];
      _Float16 hi = (_Float16)w;
      tf[H1H + (size_t)i*8 + j] = hi;
      tf[H1L + (size_t)i*8 + j] = (_Float16)(w - (float)hi);
    }
  }
  for (int i = tid; i < 64; i += nt) {
    int l = i, m = l & 15, kb = (l >> 4)*8;
    #pragma unroll
    for (int j = 0; j < 8; ++j) {
      float w = (m < 3) ? h2_w[(size_t)(kb + j)*3 + m] : 0.f;
      _Float16 hi = (_Float16)w;
      tf[H2H + (size_t)i*8 + j] = hi;
      tf[H2L + (size_t)i*8 + j] = (_Float16)(w - (float)hi);
    }
  }
  for (int i = tid; i < 4*64; i += nt) {
    int l = i & 63, mt = i >> 6;
    int o = mt*16 + (l & 15), kb = (l >> 4)*4;
    #pragma unroll
    for (int j = 0; j < 4; ++j) {
      float acc = 0.f;
      for (int m = 0; m < 64; ++m) acc += Cm[(kb + j)*64 + m]*out_w[m*64 + o];
      _Float16 hi = (_Float16)acc;
      tf[COH + (size_t)i*4 + j] = hi;
      tf[COL + (size_t)i*4 + j] = (_Float16)(acc - (float)hi);
    }
  }
}

// ============================ conv1+conv2+conv3 (packed columns) + leading RNN ============================
// R12: single change vs R11 — __launch_bounds__(320, 3) (was (320,4)).
// R11's (320,4) set the unified VGPR budget to 128; conv1's xv[4][12]+a1[10]
// peak + 32 acc AGPRs overflowed it -> scratch spill (WRITE_SIZE 15.9MB vs
// R4's 5.1MB, FETCH +2.9MB). (320,3) raises the budget to ~170; LDS (46,080 x
// 3 = 138KB) still permits 3 blocks/CU, so designed residency is unchanged.
// Geometry (R10): B-columns col = b*10 + t -> 160 = 5 full 32-col MFMA tiles,
// 100% valid; MFMAs/block 2304->1440; 320 thr = 5 waves, 1 tile/wave, 32 AGPR
// accumulators; acts rows b*10+t stride 72; 5 __syncthreads; mean via float
// overlay (stride 68).
__global__ __launch_bounds__(320, 3) void conv123_kernel(
    const float* __restrict__ x, const float* __restrict__ wsr,
    const float* __restrict__ A, float* __restrict__ hout,
    float* __restrict__ sfp)
{
  __shared__ __align__(16) _Float16 acts[2][160][72];   // 46,080 B

  const int tid = threadIdx.x;
  const int lane = tid & 63;
  const int wid = tid >> 6;

  if (blockIdx.x < NRNN) {
    // ---------------- RNN (leading blocks, waves 0-3 x 16 batches) ----------------
    if (wid >= 4) return;
    const int colb = lane & 15;
    const int q = lane >> 4;
    const size_t b = ((size_t)blockIdx.x*4 + wid)*16 + colb;

    const f32x4 av = *(const f32x4*)(A + (size_t)colb*16 + q*4);
    half4 Ahi, Alo;
    #pragma unroll
    for (int j = 0; j < 4; ++j) {
      _Float16 hi = (_Float16)av[j];
      Ahi[j] = hi;
      Alo[j] = (_Float16)(av[j] - (float)hi);
    }
    f32x4 pb0 = *(const f32x4*)(wsr + OFF_PB + 0*16 + q*4);
    f32x4 pb1 = *(const f32x4*)(wsr + OFF_PB + 1*16 + q*4);
    f32x4 pb2 = *(const f32x4*)(wsr + OFF_PB + 2*16 + q*4);
    f32x4 pb3 = *(const f32x4*)(wsr + OFF_PB + 3*16 + q*4);
    f32x4 pbb = *(const f32x4*)(wsr + OFF_PBB + q*4);

    const float* xb = x + b*400;
    half4 hh = {}, hl = {};
    f32x4 hf;
    #pragma unroll 2
    for (int t = 0; t < 100; ++t) {
      const f32x4 xv = *(const f32x4*)(xb + t*4);
      f32x4 U;
      #pragma unroll
      for (int r = 0; r < 4; ++r)
        U[r] = pbb[r] + xv[0]*pb0[r] + xv[1]*pb1[r] + xv[2]*pb2[r] + xv[3]*pb3[r];
      f32x4 u = mfma16(Alo, hh, U);
      u = mfma16(Ahi, hl, u);
      u = mfma16(Ahi, hh, u);
      #pragma unroll
      for (int r = 0; r < 4; ++r) {
        float e = __expf(2.f*u[r]);
        float hn = 1.f - 2.f/(e + 1.f);
        hf[r] = hn;
        _Float16 hi = (_Float16)hn;
        hh[r] = hi;
        hl[r] = (_Float16)(hn - (float)hi);
      }
    }
    *(f32x4*)(hout + b*16 + q*4) = hf;
    return;
  }

  // ---------------- conv path ----------------
  const size_t B0g = (size_t)(blockIdx.x - NRNN) * 16;

  // conv1: waves 0-3, 4 batches each; rows b*10+t
  if (wid < 4) {
    const float sc1 = wsr[OFF_SC1 + lane], sh1 = wsr[OFF_SH1 + lane];
    #pragma unroll
    for (int bb = 0; bb < 4; ++bb) {
      const int lb = 4*wid + bb;
      const size_t gb = B0g + lb;
      float xv[4][12];
      #pragma unroll
      for (int c = 0; c < 4; ++c) { xv[c][0] = 0.f; xv[c][11] = 0.f; }
      #pragma unroll
      for (int tt = 0; tt < 10; ++tt) {
        const f32x4 xt = *(const f32x4*)(x + gb*400 + (90 + tt)*4);
        #pragma unroll
        for (int c = 0; c < 4; ++c) xv[c][1 + tt] = xt[c];
      }
      float a1[10];
      #pragma unroll
      for (int t = 0; t < 10; ++t) a1[t] = 0.f;
      #pragma unroll
      for (int c = 0; c < 4; ++c)
        #pragma unroll
        for (int k = 0; k < 3; ++k) {
          const float wv = wsr[OFF_W1T + (c*3 + k)*64 + lane];
          #pragma unroll
          for (int t = 0; t < 10; ++t) a1[t] += wv * xv[c][t + k];
        }
      #pragma unroll
      for (int t = 0; t < 10; ++t) {
        float v = sc1*a1[t] + sh1;
        v = v > 0.f ? v : 0.f;
        _Float16 hi = (_Float16)v;
        acts[0][lb*10 + t][lane] = hi;
        acts[1][lb*10 + t][lane] = (_Float16)(v - (float)hi);
      }
    }
  }
  __syncthreads();

  // per-lane packed-column mapping
  const int col = wid*32 + (lane & 31);      // 0..159
  const int b = col / 10;
  const int tq = col - b*10;
  const int rowbase = b*10;
  const int kh8 = (lane >> 5) * 8;
  const int rq = 4 * (lane >> 5);
  const half8 z8 = {};
  const _Float16* abase = &acts[0][0][0];
  const _Float16* lbase = &acts[1][0][0];
  const _Float16* w2h = (const _Float16*)(wsr + OFF_W2H);
  const _Float16* w2l = (const _Float16*)(wsr + OFF_W2L);
  const _Float16* w3h = (const _Float16*)(wsr + OFF_W3H);
  const _Float16* w3l = (const _Float16*)(wsr + OFF_W3L);
  const int lw8 = lane*8;

  // conv2: 1 col-tile per wave, both otiles
  f32x16 acc0, acc1;
  {
    #pragma unroll
    for (int r = 0; r < 16; ++r) { acc0[r] = 0.f; acc1[r] = 0.f; }
    #pragma unroll
    for (int sk = 0; sk < 20; ++sk) {
      const int tap = sk >> 2, icb = (sk & 3)*16;
      const int t = tq + tap - 2;
      const int tc = t < 0 ? 0 : (t > 9 ? 9 : t);
      const bool valid = (t >= 0) & (t <= 9);
      const int off = (rowbase + tc)*72 + icb + kh8;
      half8 bh = *(const half8*)(abase + off);
      half8 bl = *(const half8*)(lbase + off);
      bh = valid ? bh : z8;
      bl = valid ? bl : z8;
      const half8 wh0 = *(const half8*)(w2h + (size_t)(sk*2 + 0)*512 + lw8);
      const half8 wh1 = *(const half8*)(w2h + (size_t)(sk*2 + 1)*512 + lw8);
      const half8 wl0 = *(const half8*)(w2l + (size_t)(sk*2 + 0)*512 + lw8);
      const half8 wl1 = *(const half8*)(w2l + (size_t)(sk*2 + 1)*512 + lw8);
      acc0 = mfma32(wh0, bh, acc0);
      acc0 = mfma32(wh0, bl, acc0);
      acc0 = mfma32(wl0, bh, acc0);
      acc1 = mfma32(wh1, bh, acc1);
      acc1 = mfma32(wh1, bl, acc1);
      acc1 = mfma32(wl1, bh, acc1);
    }
  }
  __syncthreads();   // all conv2 reads complete before act2 overwrites act1

  // epi2: act2 -> same LDS rows (all 160 cols valid, every lane writes)
  {
    auto epi = [&](const f32x16& ac, int ot) {
      #pragma unroll
      for (int q = 0; q < 4; ++q) {
        const int rowc = 8*q + rq + ot*32;
        const f32x4 sc = *(const f32x4*)(wsr + OFF_SC2 + rowc);
        const f32x4 sh = *(const f32x4*)(wsr + OFF_SH2 + rowc);
        half4 h4, l4;
        #pragma unroll
        for (int r = 0; r < 4; ++r) {
          float v = sc[r]*ac[4*q + r] + sh[r];
          v = v > 0.f ? v : 0.f;
          _Float16 hi = (_Float16)v;
          h4[r] = hi;
          l4[r] = (_Float16)(v - (float)hi);
        }
        *(half4*)(&acts[0][rowbase + tq][rowc]) = h4;
        *(half4*)(&acts[1][rowbase + tq][rowc]) = l4;
      }
    };
    epi(acc0, 0);
    epi(acc1, 1);
  }
  __syncthreads();   // act2 visible to all waves

  // conv3: 1 col-tile per wave, both otiles
  {
    #pragma unroll
    for (int r = 0; r < 16; ++r) { acc0[r] = 0.f; acc1[r] = 0.f; }
    #pragma unroll
    for (int sk = 0; sk < 28; ++sk) {
      const int tap = sk >> 2, icb = (sk & 3)*16;
      const int t = tq + tap - 3;
      const int tc = t < 0 ? 0 : (t > 9 ? 9 : t);
      const bool valid = (t >= 0) & (t <= 9);
      const int off = (rowbase + tc)*72 + icb + kh8;
      half8 bh = *(const half8*)(abase + off);
      half8 bl = *(const half8*)(lbase + off);
      bh = valid ? bh : z8;
      bl = valid ? bl : z8;
      const half8 wh0 = *(const half8*)(w3h + (size_t)(sk*2 + 0)*512 + lw8);
      const half8 wh1 = *(const half8*)(w3h + (size_t)(sk*2 + 1)*512 + lw8);
      const half8 wl0 = *(const half8*)(w3l + (size_t)(sk*2 + 0)*512 + lw8);
      const half8 wl1 = *(const half8*)(w3l + (size_t)(sk*2 + 1)*512 + lw8);
      acc0 = mfma32(wh0, bh, acc0);
      acc0 = mfma32(wh0, bl, acc0);
      acc0 = mfma32(wl0, bh, acc0);
      acc1 = mfma32(wh1, bh, acc1);
      acc1 = mfma32(wh1, bl, acc1);
      acc1 = mfma32(wl1, bh, acc1);
    }
  }
  __syncthreads();   // all conv3 reads complete before float overlay overwrites

  // epi3: relu'd floats to overlay av[160][68] (43,520 B <= 46,080 B region)
  {
    float* av = (float*)&acts[0][0][0];
    auto epi = [&](const f32x16& ac, int ot) {
      #pragma unroll
      for (int q = 0; q < 4; ++q) {
        const int rowc = 8*q + rq + ot*32;
        const f32x4 sc = *(const f32x4*)(wsr + OFF_SC3 + rowc);
        const f32x4 sh = *(const f32x4*)(wsr + OFF_SH3 + rowc);
        f32x4 v;
        #pragma unroll
        for (int r = 0; r < 4; ++r) {
          float t2 = sc[r]*ac[4*q + r] + sh[r];
          v[r] = t2 > 0.f ? t2 : 0.f;
        }
        *(f32x4*)(av + (rowbase + tq)*68 + rowc) = v;
      }
    };
    epi(acc0, 0);
    epi(acc1, 1);
  }
  __syncthreads();

  // mean over t: 1024 (b,ch) pairs over 320 threads -> sfp
  {
    const float* av = (const float*)&acts[0][0][0];
    for (int i = tid; i < 1024; i += 320) {
      const int bb = i >> 6, ch = i & 63;
      float s = 0.f;
      #pragma unroll
      for (int t = 0; t < 10; ++t) s += av[(bb*10 + t)*68 + ch];
      sfp[(B0g + bb)*64 + ch] = 0.1f * s;
    }
  }
}

// ============================ tail (MFMA, 16 batches/wave) — R4 verified ============================
#define CMBH 0
#define CMBL 2176
#define T1H  4352
#define T1L  5504
#define FLH  6656
#define FLL  7808
#define RH   8960
#define RL   9600
__global__ __launch_bounds__(256) void tail_kernel(
    const float* __restrict__ wsr,
    const float* __restrict__ g1_b, const float* __restrict__ g2_b,
    const float* __restrict__ h1_b, const float* __restrict__ h2_b,
    const float* __restrict__ out_b, float* __restrict__ out)
{
  __shared__ __align__(16) _Float16 sWF[TFH];
  __shared__ __align__(16) _Float16 sAct[4*10240];

  const int tid = threadIdx.x;
  const int lane = tid & 63;
  const int wid = tid >> 6;
  const int n = lane & 15;
  const int q = lane >> 4;
  const int B0 = blockIdx.x*64 + wid*16;

  {
    const f32x4* src = (const f32x4*)(wsr + OFF_TF);
    f32x4* dst = (f32x4*)sWF;
    for (int i = tid; i < TFH/8; i += 256) dst[i] = src[i];
  }
  __syncthreads();

  _Float16* wa = sAct + wid*10240;
  const float* sf = wsr + OFF_SF;
  const float* hws = wsr + OFF_H;

  const f32x4 hv = *(const f32x4*)(hws + (size_t)(B0 + n)*16 + q*4);
  half4 hh, hl;
  #pragma unroll
  for (int j = 0; j < 4; ++j) {
    _Float16 hi = (_Float16)hv[j];
    hh[j] = hi;
    hl[j] = (_Float16)(hv[j] - (float)hi);
  }
  f32x4 lc[4];
  #pragma unroll
  for (int mt = 0; mt < 4; ++mt) {
    lc[mt] = *(const f32x4*)(out_b + mt*16 + q*4);
    const half4 ah = *(const half4*)(sWF + COH + (size_t)(mt*64 + lane)*4);
    const half4 al = *(const half4*)(sWF + COL + (size_t)(mt*64 + lane)*4);
    lc[mt] = mfma16(al, hh, lc[mt]);
    lc[mt] = mfma16(ah, hl, lc[mt]);
    lc[mt] = mfma16(ah, hh, lc[mt]);
  }
  f32x4 sfv[4];
  #pragma unroll
  for (int mt = 0; mt < 4; ++mt) {
    sfv[mt] = *(const f32x4*)(sf + (size_t)(B0 + n)*64 + mt*16 + q*4);
    half4 sh4, sl4, lh4, ll4;
    #pragma unroll
    for (int r = 0; r < 4; ++r) {
      _Float16 hi = (_Float16)sfv[mt][r];
      sh4[r] = hi; sl4[r] = (_Float16)(sfv[mt][r] - (float)hi);
      _Float16 hi2 = (_Float16)lc[mt][r];
      lh4[r] = hi2; ll4[r] = (_Float16)(lc[mt][r] - (float)hi2);
    }
    *(half4*)(wa + CMBH + n*136 + mt*16 + q*4) = sh4;
    *(half4*)(wa + CMBL + n*136 + mt*16 + q*4) = sl4;
    *(half4*)(wa + CMBH + n*136 + 64 + mt*16 + q*4) = lh4;
    *(half4*)(wa + CMBL + n*136 + 64 + mt*16 + q*4) = ll4;
  }
  f32x4 u1[4];
  #pragma unroll
  for (int mt = 0; mt < 4; ++mt) u1[mt] = *(const f32x4*)(g1_b + mt*16 + q*4);
  #pragma unroll
  for (int ks = 0; ks < 4; ++ks) {
    const half8 bh = *(const half8*)(wa + CMBH + n*136 + ks*32 + q*8);
    const half8 bl = *(const half8*)(wa + CMBL + n*136 + ks*32 + q*8);
    #pragma unroll
    for (int mt = 0; mt < 4; ++mt) {
      const half8 ah = *(const half8*)(sWF + G1H + (size_t)((mt*4 + ks)*64 + lane)*8);
      const half8 al = *(const half8*)(sWF + G1L + (size_t)((mt*4 + ks)*64 + lane)*8);
      u1[mt] = mfma16k32(al, bh, u1[mt]);
      u1[mt] = mfma16k32(ah, bl, u1[mt]);
      u1[mt] = mfma16k32(ah, bh, u1[mt]);
    }
  }
  #pragma unroll
  for (int mt = 0; mt < 4; ++mt) {
    half4 th4, tl4;
    #pragma unroll
    for (int r = 0; r < 4; ++r) {
      float e = __expf(2.f*u1[mt][r]);
      float t1 = 1.f - 2.f/(e + 1.f);
      _Float16 hi = (_Float16)t1;
      th4[r] = hi; tl4[r] = (_Float16)(t1 - (float)hi);
    }
    *(half4*)(wa + T1H + n*72 + mt*16 + q*4) = th4;
    *(half4*)(wa + T1L + n*72 + mt*16 + q*4) = tl4;
  }
  f32x4 u2[4];
  #pragma unroll
  for (int mt = 0; mt < 4; ++mt) u2[mt] = *(const f32x4*)(g2_b + mt*16 + q*4);
  #pragma unroll
  for (int ks = 0; ks < 2; ++ks) {
    const half8 bh = *(const half8*)(wa + T1H + n*72 + ks*32 + q*8);
    const half8 bl = *(const half8*)(wa + T1L + n*72 + ks*32 + q*8);
    #pragma unroll
    for (int mt = 0; mt < 4; ++mt) {
      const half8 ah = *(const half8*)(sWF + G2H + (size_t)((mt*2 + ks)*64 + lane)*8);
      const half8 al = *(const half8*)(sWF + G2L + (size_t)((mt*2 + ks)*64 + lane)*8);
      u2[mt] = mfma16k32(al, bh, u2[mt]);
      u2[mt] = mfma16k32(ah, bl, u2[mt]);
      u2[mt] = mfma16k32(ah, bh, u2[mt]);
    }
  }
  #pragma unroll
  for (int mt = 0; mt < 4; ++mt) {
    half4 fh4, fl4;
    #pragma unroll
    for (int r = 0; r < 4; ++r) {
      float gate = 1.f/(1.f + __expf(-u2[mt][r]));
      float f = sfv[mt][r] * gate;
      _Float16 hi = (_Float16)f;
      fh4[r] = hi; fl4[r] = (_Float16)(f - (float)hi);
    }
    *(half4*)(wa + FLH + n*72 + mt*16 + q*4) = fh4;
    *(half4*)(wa + FLL + n*72 + mt*16 + q*4) = fl4;
  }
  f32x4 u3[2];
  #pragma unroll
  for (int mt = 0; mt < 2; ++mt) u3[mt] = *(const f32x4*)(h1_b + mt*16 + q*4);
  #pragma unroll
  for (int ks = 0; ks < 2; ++ks) {
    const half8 bh = *(const half8*)(wa + FLH + n*72 + ks*32 + q*8);
    const half8 bl = *(const half8*)(wa + FLL + n*72 + ks*32 + q*8);
    #pragma unroll
    for (int mt = 0; mt < 2; ++mt) {
      const half8 ah = *(const half8*)(sWF + H1H + (size_t)((mt*2 + ks)*64 + lane)*8);
      const half8 al = *(const half8*)(sWF + H1L + (size_t)((mt*2 + ks)*64 + lane)*8);
      u3[mt] = mfma16k32(al, bh, u3[mt]);
      u3[mt] = mfma16k32(ah, bl, u3[mt]);
      u3[mt] = mfma16k32(ah, bh, u3[mt]);
    }
  }
  #pragma unroll
  for (int mt = 0; mt < 2; ++mt) {
    half4 rh4, rl4;
    #pragma unroll
    for (int r = 0; r < 4; ++r) {
      float v = fmaxf(u3[mt][r], 0.f);
      _Float16 hi = (_Float16)v;
      rh4[r] = hi; rl4[r] = (_Float16)(v - (float)hi);
    }
    *(half4*)(wa + RH + n*40 + mt*16 + q*4) = rh4;
    *(half4*)(wa + RL + n*40 + mt*16 + q*4) = rl4;
  }
  {
    f32x4 u4;
    if (q == 0) { u4[0] = h2_b[0]; u4[1] = h2_b[1]; u4[2] = h2_b[2]; u4[3] = 0.f; }
    else { u4[0] = 0.f; u4[1] = 0.f; u4[2] = 0.f; u4[3] = 0.f; }
    const half8 bh = *(const half8*)(wa + RH + n*40 + q*8);
    const half8 bl = *(const half8*)(wa + RL + n*40 + q*8);
    const half8 ah = *(const half8*)(sWF + H2H + (size_t)lane*8);
    const half8 al = *(const half8*)(sWF + H2L + (size_t)lane*8);
    u4 = mfma16k32(al, bh, u4);
    u4 = mfma16k32(ah, bl, u4);
    u4 = mfma16k32(ah, bh, u4);
    if (q == 0) {
      out[(size_t)(B0 + n)*3 + 0] = u4[0];
      out[(size_t)(B0 + n)*3 + 1] = u4[1];
      out[(size_t)(B0 + n)*3 + 2] = u4[2];
    }
  }
}

// ============================ launch ============================
extern "C" void kernel_launch(void* const* d_in, const int* in_sizes, int n_in,
                              void* d_out, int out_size, void* d_ws, size_t ws_size,
                              hipStream_t stream) {
  const float* x       = (const float*)d_in[0];
  const float* conv1_w = (const float*)d_in[1];
  const float* conv1_b = (const float*)d_in[2];
  const float* conv2_w = (const float*)d_in[3];
  const float* conv2_b = (const float*)d_in[4];
  const float* conv3_w = (const float*)d_in[5];
  const float* conv3_b = (const float*)d_in[6];
  const float* bn1_g   = (const float*)d_in[7];
  const float* bn1_b   = (const float*)d_in[8];
  const float* bn2_g   = (const float*)d_in[9];
  const float* bn2_b   = (const float*)d_in[10];
  const float* bn3_g   = (const float*)d_in[11];
  const float* bn3_b   = (const float*)d_in[12];
  const float* proj_w  = (const float*)d_in[13];
  const float* proj_b  = (const float*)d_in[14];
  const float* A       = (const float*)d_in[15];
  const float* Bm      = (const float*)d_in[16];
  const float* Cm      = (const float*)d_in[17];
  const float* out_w   = (const float*)d_in[18];
  const float* out_b   = (const float*)d_in[19];
  const float* g1_w    = (const float*)d_in[20];
  const float* g1_b    = (const float*)d_in[21];
  const float* g2_w    = (const float*)d_in[22];
  const float* g2_b    = (const float*)d_in[23];
  const float* h1_w    = (const float*)d_in[24];
  const float* h1_b    = (const float*)d_in[25];
  const float* h2_w    = (const float*)d_in[26];
  const float* h2_b    = (const float*)d_in[27];
  float* ws = (float*)d_ws;
  float* out = (float*)d_out;

  prep_kernel<<<64, 256, 0, stream>>>(conv1_w, conv1_b, conv2_w, conv2_b,
      conv3_w, conv3_b, bn1_g, bn1_b, bn2_g, bn2_b, bn3_g, bn3_b,
      proj_w, proj_b, A, Bm, Cm, out_w, g1_w, g2_w, h1_w, h2_w, ws);

  conv123_kernel<<<NRNN + NB/16, 320, 0, stream>>>(x, ws, A, ws + OFF_H,
      ws + OFF_SF);

  tail_kernel<<<NB/64, 256, 0, stream>>>(ws, g1_b, g2_b, h1_b, h2_b, out_b, out);
}

// Round 13
// 223.792 us; speedup vs baseline: 1.2954x; 1.0411x over previous
//
#include <hip/hip_runtime.h>
#include <cstddef>

#define NB 16384
#define TS 720    // act batch stride in halves (10 slots * 72)
#define NRNN (NB/64)   // 256 leading rnn blocks (4 waves x 16 batches each)

typedef __attribute__((ext_vector_type(8))) _Float16 half8;
typedef __attribute__((ext_vector_type(4))) _Float16 half4;
typedef __attribute__((ext_vector_type(4))) float f32x4;
typedef __attribute__((ext_vector_type(2))) float f32x2;
typedef __attribute__((ext_vector_type(16))) float f32x16;

// ---- ws float offsets ----
#define OFF_W1T 0
#define OFF_SC1 768
#define OFF_SH1 832
#define OFF_SC2 896
#define OFF_SH2 960
#define OFF_SC3 1024
#define OFF_SH3 1088
#define OFF_PB  1152
#define OFF_PBB 1216
#define OFF_W2H 2304                   // w2 hi 10240 f, then lo 10240 f (contiguous)
#define OFF_W2L 12544
#define OFF_W3H 22784                  // w3 hi 14336 f, then lo 14336 f (contiguous)
#define OFF_W3L 37120
#define OFF_SF  51456                  // NB*64
#define OFF_H   (51456 + NB*64)        // NB*16 -> ends 1362176
#define OFF_TF  1362176                // tail frags: 31744 halves = 15872 floats

// tail frag half-offsets within OFF_TF region
#define G1H 0
#define G1L 8192
#define G2H 16384
#define G2L 20480
#define H1H 24576
#define H1L 26624
#define H2H 28672
#define H2L 29184
#define COH 29696
#define COL 30720
#define TFH 31744   // total halves

static __device__ __forceinline__ f32x16 mfma32(half8 a, half8 b, f32x16 c) {
  return __builtin_amdgcn_mfma_f32_32x32x16_f16(a, b, c, 0, 0, 0);
}
static __device__ __forceinline__ f32x4 mfma16(half4 a, half4 b, f32x4 c) {
  return __builtin_amdgcn_mfma_f32_16x16x16f16(a, b, c, 0, 0, 0);
}
static __device__ __forceinline__ f32x4 mfma16k32(half8 a, half8 b, f32x4 c) {
  return __builtin_amdgcn_mfma_f32_16x16x32_f16(a, b, c, 0, 0, 0);
}

// ============================ prep ============================
__global__ __launch_bounds__(256) void prep_kernel(
    const float* __restrict__ conv1_w, const float* __restrict__ conv1_b,
    const float* __restrict__ conv2_w, const float* __restrict__ conv2_b,
    const float* __restrict__ conv3_w, const float* __restrict__ conv3_b,
    const float* __restrict__ bn1_g, const float* __restrict__ bn1_b,
    const float* __restrict__ bn2_g, const float* __restrict__ bn2_b,
    const float* __restrict__ bn3_g, const float* __restrict__ bn3_b,
    const float* __restrict__ proj_w, const float* __restrict__ proj_b,
    const float* __restrict__ A, const float* __restrict__ Bm,
    const float* __restrict__ Cm, const float* __restrict__ out_w,
    const float* __restrict__ g1_w, const float* __restrict__ g2_w,
    const float* __restrict__ h1_w, const float* __restrict__ h2_w,
    float* __restrict__ ws)
{
  int tid = blockIdx.x * blockDim.x + threadIdx.x;
  int nt = gridDim.x * blockDim.x;
  const float s = rsqrtf(1.0f + 1e-5f);

  for (int i = tid; i < 64*12; i += nt) {
    int o = i & 63, rk = i >> 6;
    ws[OFF_W1T + i] = conv1_w[o*12 + rk];
  }
  for (int o = tid; o < 64; o += nt) {
    float s1 = bn1_g[o]*s, s2 = bn2_g[o]*s, s3 = bn3_g[o]*s;
    ws[OFF_SC1+o] = s1; ws[OFF_SH1+o] = s1*conv1_b[o] + bn1_b[o];
    ws[OFF_SC2+o] = s2; ws[OFF_SH2+o] = s2*conv2_b[o] + bn2_b[o];
    ws[OFF_SC3+o] = s3; ws[OFF_SH3+o] = s3*conv3_b[o] + bn3_b[o];
  }
  // conv2 A-fragments (32x32x16), hi/lo split
  {
    _Float16* w2h = (_Float16*)(ws + OFF_W2H);
    _Float16* w2l = (_Float16*)(ws + OFF_W2L);
    for (int i = tid; i < 20*2*64; i += nt) {
      int lane = i & 63, ot = (i >> 6) & 1, sk = i >> 7;
      int tap = sk >> 2, ic0 = (sk & 3)*16 + (lane >> 5)*8;
      int o = ot*32 + (lane & 31);
      #pragma unroll
      for (int j = 0; j < 8; ++j) {
        float w = conv2_w[o*320 + (ic0 + j)*5 + tap];
        _Float16 hi = (_Float16)w;
        w2h[(size_t)i*8 + j] = hi;
        w2l[(size_t)i*8 + j] = (_Float16)(w - (float)hi);
      }
    }
  }
  {
    _Float16* w3h = (_Float16*)(ws + OFF_W3H);
    _Float16* w3l = (_Float16*)(ws + OFF_W3L);
    for (int i = tid; i < 28*2*64; i += nt) {
      int lane = i & 63, ot = (i >> 6) & 1, sk = i >> 7;
      int tap = sk >> 2, ic0 = (sk & 3)*16 + (lane >> 5)*8;
      int o = ot*32 + (lane & 31);
      #pragma unroll
      for (int j = 0; j < 8; ++j) {
        float w = conv3_w[o*448 + (ic0 + j)*7 + tap];
        _Float16 hi = (_Float16)w;
        w3h[(size_t)i*8 + j] = hi;
        w3l[(size_t)i*8 + j] = (_Float16)(w - (float)hi);
      }
    }
  }
  // PB[c][j], PBB[j]
  for (int i = tid; i < 64; i += nt) {
    int c = i >> 4, j = i & 15;
    float acc = 0.f;
    for (int m = 0; m < 64; ++m) acc += proj_w[c*64+m]*Bm[m*16+j];
    ws[OFF_PB + i] = acc;
  }
  for (int j = tid; j < 16; j += nt) {
    float acc = 0.f;
    for (int m = 0; m < 64; ++m) acc += proj_b[m]*Bm[m*16+j];
    ws[OFF_PBB + j] = acc;
  }

  // ---- tail MFMA fragments (hi/lo) ----
  _Float16* tf = (_Float16*)(ws + OFF_TF);
  for (int i = tid; i < 16*64; i += nt) {
    int l = i & 63, f = i >> 6, mt = f >> 2, ks = f & 3;
    int o = mt*16 + (l & 15), kb = ks*32 + (l >> 4)*8;
    #pragma unroll
    for (int j = 0; j < 8; ++j) {
      float w = g1_w[(size_t)(kb + j)*64 + o];
      _Float16 hi = (_Float16)w;
      tf[G1H + (size_t)i*8 + j] = hi;
      tf[G1L + (size_t)i*8 + j] = (_Float16)(w - (float)hi);
    }
  }
  for (int i = tid; i < 8*64; i += nt) {
    int l = i & 63, f = i >> 6, mt = f >> 1, ks = f & 1;
    int o = mt*16 + (l & 15), kb = ks*32 + (l >> 4)*8;
    #pragma unroll
    for (int j = 0; j < 8; ++j) {
      float w = g2_w[(size_t)(kb + j)*64 + o];
      _Float16 hi = (_Float16)w;
      tf[G2H + (size_t)i*8 + j] = hi;
      tf[G2L + (size_t)i*8 + j] = (_Float16)(w - (float)hi);
    }
  }
  for (int i = tid; i < 4*64; i += nt) {
    int l = i & 63, f = i >> 6, mt = f >> 1, ks = f & 1;
    int hx = mt*16 + (l & 15), kb = ks*32 + (l >> 4)*8;
    #pragma unroll
    for (int j = 0; j < 8; ++j) {
      float w = h1_w[(size_t)(kb + j)*32 + hx];
      _Float16 hi = (_Float16)w;
      tf[H1H + (size_t)i*8 + j] = hi;
      tf[H1L + (size_t)i*8 + j] = (_Float16)(w - (float)hi);
    }
  }
  for (int i = tid; i < 64; i += nt) {
    int l = i, m = l & 15, kb = (l >> 4)*8;
    #pragma unroll
    for (int j = 0; j < 8; ++j) {
      float w = (m < 3) ? h2_w[(size_t)(kb + j)*3 + m] : 0.f;
      _Float16 hi = (_Float16)w;
      tf[H2H + (size_t)i*8 + j] = hi;
      tf[H2L + (size_t)i*8 + j] = (_Float16)(w - (float)hi);
    }
  }
  for (int i = tid; i < 4*64; i += nt) {
    int l = i & 63, mt = i >> 6;
    int o = mt*16 + (l & 15), kb = (l >> 4)*4;
    #pragma unroll
    for (int j = 0; j < 4; ++j) {
      float acc = 0.f;
      for (int m = 0; m < 64; ++m) acc += Cm[(kb + j)*64 + m]*out_w[m*64 + o];
      _Float16 hi = (_Float16)acc;
      tf[COH + (size_t)i*4 + j] = hi;
      tf[COL + (size_t)i*4 + j] = (_Float16)(acc - (float)hi);
    }
  }
}

// ============================ fused conv1+conv2+conv3 + leading RNN ============================
// FINAL: exact R4 configuration — the session-best (227.9 us total, verified
// twice). 4 batches/wave (2 MFMA batch-pairs), padded-72 LDS,
// launch_bounds(256,3): VGPR 80 + 64 AGPR fits the 170-reg budget, no spill.
// Plateau note (R5/R10/R12 falsification matrix): conv123 dur is invariant to
// MFMA volume (-37.5%), spill removal, bank conflicts (2.1M->0.8M), load
// scheduling, and occupancy 17-49% — a latency plateau at ~110us that
// source-level changes could not break; the 2x weight amortization (R1->R4)
// was the only lever that moved it.
__global__ __launch_bounds__(256, 3) void conv123_kernel(
    const float* __restrict__ x, const float* __restrict__ wsr,
    const float* __restrict__ A, float* __restrict__ hout,
    float* __restrict__ sfp)
{
  __shared__ __align__(16) _Float16 ah[16][TS], al[16][TS];

  const int tid = threadIdx.x;
  const int lane = tid & 63;
  const int wid = tid >> 6;

  if (blockIdx.x < NRNN) {
    // ---------------- RNN (leading blocks, 4 waves x 16 batches) ----------------
    const int colb = lane & 15;
    const int q = lane >> 4;
    const size_t b = ((size_t)blockIdx.x*4 + wid)*16 + colb;

    const f32x4 av = *(const f32x4*)(A + (size_t)(lane & 15)*16 + q*4);
    half4 Ahi, Alo;
    #pragma unroll
    for (int j = 0; j < 4; ++j) {
      _Float16 hi = (_Float16)av[j];
      Ahi[j] = hi;
      Alo[j] = (_Float16)(av[j] - (float)hi);
    }
    f32x4 pb0 = *(const f32x4*)(wsr + OFF_PB + 0*16 + q*4);
    f32x4 pb1 = *(const f32x4*)(wsr + OFF_PB + 1*16 + q*4);
    f32x4 pb2 = *(const f32x4*)(wsr + OFF_PB + 2*16 + q*4);
    f32x4 pb3 = *(const f32x4*)(wsr + OFF_PB + 3*16 + q*4);
    f32x4 pbb = *(const f32x4*)(wsr + OFF_PBB + q*4);

    const float* xb = x + b*400;
    half4 hh = {}, hl = {};
    f32x4 hf;
    #pragma unroll 2
    for (int t = 0; t < 100; ++t) {
      const f32x4 xv = *(const f32x4*)(xb + t*4);
      f32x4 U;
      #pragma unroll
      for (int r = 0; r < 4; ++r)
        U[r] = pbb[r] + xv[0]*pb0[r] + xv[1]*pb1[r] + xv[2]*pb2[r] + xv[3]*pb3[r];
      f32x4 u = mfma16(Alo, hh, U);
      u = mfma16(Ahi, hl, u);
      u = mfma16(Ahi, hh, u);
      #pragma unroll
      for (int r = 0; r < 4; ++r) {
        float e = __expf(2.f*u[r]);
        float hn = 1.f - 2.f/(e + 1.f);
        hf[r] = hn;
        _Float16 hi = (_Float16)hn;
        hh[r] = hi;
        hl[r] = (_Float16)(hn - (float)hi);
      }
    }
    *(f32x4*)(hout + b*16 + q*4) = hf;
    return;
  }

  // ---------------- conv path (4 batches/wave = 2 batch-pairs) ----------------
  const int n = lane & 15;
  const int nc = (n < 10) ? n : 9;
  const int kh8 = (lane >> 5) * 8;
  const int rq = 4 * (lane >> 5);
  const int lbA = 4*wid + ((lane >> 4) & 1);   // pair A: batches 4w, 4w+1
  const int lbB = lbA + 2;                     // pair B: batches 4w+2, 4w+3
  const half8 z8 = {};
  const size_t B0g = (size_t)(blockIdx.x - NRNN) * 16;

  // conv1 for this wave's 4 batches (writes wave-private LDS rows)
  {
    const float sc1 = wsr[OFF_SC1 + lane], sh1 = wsr[OFF_SH1 + lane];
    #pragma unroll
    for (int bb = 0; bb < 4; ++bb) {
      const int lb = 4*wid + bb;
      const size_t gb = B0g + lb;
      float xv[4][12];
      #pragma unroll
      for (int c = 0; c < 4; ++c) { xv[c][0] = 0.f; xv[c][11] = 0.f; }
      #pragma unroll
      for (int tt = 0; tt < 10; ++tt) {
        const f32x4 xt = *(const f32x4*)(x + gb*400 + (90 + tt)*4);
        #pragma unroll
        for (int c = 0; c < 4; ++c) xv[c][1 + tt] = xt[c];
      }
      float a1[10];
      #pragma unroll
      for (int t = 0; t < 10; ++t) a1[t] = 0.f;
      #pragma unroll
      for (int c = 0; c < 4; ++c)
        #pragma unroll
        for (int k = 0; k < 3; ++k) {
          const float wv = wsr[OFF_W1T + (c*3 + k)*64 + lane];
          #pragma unroll
          for (int t = 0; t < 10; ++t) a1[t] += wv * xv[c][t + k];
        }
      #pragma unroll
      for (int t = 0; t < 10; ++t) {
        float v = sc1*a1[t] + sh1;
        v = v > 0.f ? v : 0.f;
        _Float16 hi = (_Float16)v;
        ah[lb][t*72 + lane] = hi;
        al[lb][t*72 + lane] = (_Float16)(v - (float)hi);
      }
    }
  }

  const _Float16* bhpA = &ah[lbA][0];
  const _Float16* blpA = &al[lbA][0];
  const _Float16* bhpB = &ah[lbB][0];
  const _Float16* blpB = &al[lbB][0];
  const _Float16* w2h = (const _Float16*)(wsr + OFF_W2H);
  const _Float16* w2l = (const _Float16*)(wsr + OFF_W2L);
  const _Float16* w3h = (const _Float16*)(wsr + OFF_W3H);
  const _Float16* w3l = (const _Float16*)(wsr + OFF_W3L);
  const int lw8 = lane*8;

  // conv2: both otiles x both batch-pairs; weights loaded once per sk
  {
    f32x16 a0A, a1A, a0B, a1B;
    #pragma unroll
    for (int r = 0; r < 16; ++r) { a0A[r] = 0.f; a1A[r] = 0.f; a0B[r] = 0.f; a1B[r] = 0.f; }
    #pragma unroll
    for (int sk = 0; sk < 20; ++sk) {
      const int tap = sk >> 2, icb = (sk & 3)*16;
      const int t = nc + tap - 2;
      const int tc = t < 0 ? 0 : (t > 9 ? 9 : t);
      const bool valid = (t >= 0) & (t <= 9);
      const int off = tc*72 + icb + kh8;
      half8 bhA = *(const half8*)(bhpA + off);
      half8 blA = *(const half8*)(blpA + off);
      half8 bhB = *(const half8*)(bhpB + off);
      half8 blB = *(const half8*)(blpB + off);
      bhA = valid ? bhA : z8;
      blA = valid ? blA : z8;
      bhB = valid ? bhB : z8;
      blB = valid ? blB : z8;
      const half8 wh0 = *(const half8*)(w2h + (size_t)(sk*2 + 0)*512 + lw8);
      const half8 wh1 = *(const half8*)(w2h + (size_t)(sk*2 + 1)*512 + lw8);
      const half8 wl0 = *(const half8*)(w2l + (size_t)(sk*2 + 0)*512 + lw8);
      const half8 wl1 = *(const half8*)(w2l + (size_t)(sk*2 + 1)*512 + lw8);
      a0A = mfma32(wh0, bhA, a0A);
      a0A = mfma32(wh0, blA, a0A);
      a0A = mfma32(wl0, bhA, a0A);
      a1A = mfma32(wh1, bhA, a1A);
      a1A = mfma32(wh1, blA, a1A);
      a1A = mfma32(wl1, bhA, a1A);
      a0B = mfma32(wh0, bhB, a0B);
      a0B = mfma32(wh0, blB, a0B);
      a0B = mfma32(wl0, bhB, a0B);
      a1B = mfma32(wh1, bhB, a1B);
      a1B = mfma32(wh1, blB, a1B);
      a1B = mfma32(wl1, bhB, a1B);
    }
    // epi2: act2 written over act1 rows (wave-private; per-wave DS ops are
    // in-order and the writes data-depend on all reads via the accumulators)
    if (n < 10) {
      auto epi = [&](const f32x16& ac, int ot, int lb) {
        #pragma unroll
        for (int q = 0; q < 4; ++q) {
          const int rowb = 8*q + rq + ot*32;
          const f32x4 sc = *(const f32x4*)(wsr + OFF_SC2 + rowb);
          const f32x4 sh = *(const f32x4*)(wsr + OFF_SH2 + rowb);
          half4 h4, l4;
          #pragma unroll
          for (int r = 0; r < 4; ++r) {
            float v = sc[r]*ac[4*q + r] + sh[r];
            v = v > 0.f ? v : 0.f;
            _Float16 hi = (_Float16)v;
            h4[r] = hi;
            l4[r] = (_Float16)(v - (float)hi);
          }
          *(half4*)(&ah[lb][n*72 + rowb]) = h4;
          *(half4*)(&al[lb][n*72 + rowb]) = l4;
        }
      };
      epi(a0A, 0, lbA);
      epi(a1A, 1, lbA);
      epi(a0B, 0, lbB);
      epi(a1B, 1, lbB);
    }
  }

  // conv3: both otiles x both batch-pairs; weights loaded once per sk
  {
    f32x16 b0A, b1A, b0B, b1B;
    #pragma unroll
    for (int r = 0; r < 16; ++r) { b0A[r] = 0.f; b1A[r] = 0.f; b0B[r] = 0.f; b1B[r] = 0.f; }
    #pragma unroll
    for (int sk = 0; sk < 28; ++sk) {
      const int tap = sk >> 2, icb = (sk & 3)*16;
      const int t = nc + tap - 3;
      const int tc = t < 0 ? 0 : (t > 9 ? 9 : t);
      const bool valid = (t >= 0) & (t <= 9);
      const int off = tc*72 + icb + kh8;
      half8 bhA = *(const half8*)(bhpA + off);
      half8 blA = *(const half8*)(blpA + off);
      half8 bhB = *(const half8*)(bhpB + off);
      half8 blB = *(const half8*)(blpB + off);
      bhA = valid ? bhA : z8;
      blA = valid ? blA : z8;
      bhB = valid ? bhB : z8;
      blB = valid ? blB : z8;
      const half8 wh0 = *(const half8*)(w3h + (size_t)(sk*2 + 0)*512 + lw8);
      const half8 wh1 = *(const half8*)(w3h + (size_t)(sk*2 + 1)*512 + lw8);
      const half8 wl0 = *(const half8*)(w3l + (size_t)(sk*2 + 0)*512 + lw8);
      const half8 wl1 = *(const half8*)(w3l + (size_t)(sk*2 + 1)*512 + lw8);
      b0A = mfma32(wh0, bhA, b0A);
      b0A = mfma32(wh0, blA, b0A);
      b0A = mfma32(wl0, bhA, b0A);
      b1A = mfma32(wh1, bhA, b1A);
      b1A = mfma32(wh1, blA, b1A);
      b1A = mfma32(wl1, bhA, b1A);
      b0B = mfma32(wh0, bhB, b0B);
      b0B = mfma32(wh0, blB, b0B);
      b0B = mfma32(wl0, bhB, b0B);
      b1B = mfma32(wh1, bhB, b1B);
      b1B = mfma32(wh1, blB, b1B);
      b1B = mfma32(wl1, bhB, b1B);
    }
    auto epi = [&](const f32x16& ac, int ot, int lb) {
      #pragma unroll
      for (int q = 0; q < 4; ++q) {
        const int rowb = 8*q + rq + ot*32;
        const f32x4 sc = *(const f32x4*)(wsr + OFF_SC3 + rowb);
        const f32x4 sh = *(const f32x4*)(wsr + OFF_SH3 + rowb);
        f32x4 v;
        #pragma unroll
        for (int r = 0; r < 4; ++r) {
          float t2 = sc[r]*ac[4*q + r] + sh[r];
          t2 = t2 > 0.f ? t2 : 0.f;
          v[r] = (n < 10) ? t2 : 0.f;
        }
        #pragma unroll
        for (int r = 0; r < 4; ++r) {
          v[r] += __shfl_xor(v[r], 1, 16);
          v[r] += __shfl_xor(v[r], 2, 16);
          v[r] += __shfl_xor(v[r], 4, 16);
          v[r] += __shfl_xor(v[r], 8, 16);
        }
        if (n == 0)
          *(f32x4*)(sfp + (B0g + lb)*64 + rowb) = v * 0.1f;
      }
    };
    epi(b0A, 0, lbA);
    epi(b1A, 1, lbA);
    epi(b0B, 0, lbB);
    epi(b1B, 1, lbB);
  }
}

// ============================ tail (MFMA, 16 batches/wave) — R4 verified ============================
#define CMBH 0
#define CMBL 2176
#define T1H  4352
#define T1L  5504
#define FLH  6656
#define FLL  7808
#define RH   8960
#define RL   9600
__global__ __launch_bounds__(256) void tail_kernel(
    const float* __restrict__ wsr,
    const float* __restrict__ g1_b, const float* __restrict__ g2_b,
    const float* __restrict__ h1_b, const float* __restrict__ h2_b,
    const float* __restrict__ out_b, float* __restrict__ out)
{
  __shared__ __align__(16) _Float16 sWF[TFH];
  __shared__ __align__(16) _Float16 sAct[4*10240];

  const int tid = threadIdx.x;
  const int lane = tid & 63;
  const int wid = tid >> 6;
  const int n = lane & 15;
  const int q = lane >> 4;
  const int B0 = blockIdx.x*64 + wid*16;

  {
    const f32x4* src = (const f32x4*)(wsr + OFF_TF);
    f32x4* dst = (f32x4*)sWF;
    for (int i = tid; i < TFH/8; i += 256) dst[i] = src[i];
  }
  __syncthreads();

  _Float16* wa = sAct + wid*10240;
  const float* sf = wsr + OFF_SF;
  const float* hws = wsr + OFF_H;

  const f32x4 hv = *(const f32x4*)(hws + (size_t)(B0 + n)*16 + q*4);
  half4 hh, hl;
  #pragma unroll
  for (int j = 0; j < 4; ++j) {
    _Float16 hi = (_Float16)hv[j];
    hh[j] = hi;
    hl[j] = (_Float16)(hv[j] - (float)hi);
  }
  f32x4 lc[4];
  #pragma unroll
  for (int mt = 0; mt < 4; ++mt) {
    lc[mt] = *(const f32x4*)(out_b + mt*16 + q*4);
    const half4 ah = *(const half4*)(sWF + COH + (size_t)(mt*64 + lane)*4);
    const half4 al = *(const half4*)(sWF + COL + (size_t)(mt*64 + lane)*4);
    lc[mt] = mfma16(al, hh, lc[mt]);
    lc[mt] = mfma16(ah, hl, lc[mt]);
    lc[mt] = mfma16(ah, hh, lc[mt]);
  }
  f32x4 sfv[4];
  #pragma unroll
  for (int mt = 0; mt < 4; ++mt) {
    sfv[mt] = *(const f32x4*)(sf + (size_t)(B0 + n)*64 + mt*16 + q*4);
    half4 sh4, sl4, lh4, ll4;
    #pragma unroll
    for (int r = 0; r < 4; ++r) {
      _Float16 hi = (_Float16)sfv[mt][r];
      sh4[r] = hi; sl4[r] = (_Float16)(sfv[mt][r] - (float)hi);
      _Float16 hi2 = (_Float16)lc[mt][r];
      lh4[r] = hi2; ll4[r] = (_Float16)(lc[mt][r] - (float)hi2);
    }
    *(half4*)(wa + CMBH + n*136 + mt*16 + q*4) = sh4;
    *(half4*)(wa + CMBL + n*136 + mt*16 + q*4) = sl4;
    *(half4*)(wa + CMBH + n*136 + 64 + mt*16 + q*4) = lh4;
    *(half4*)(wa + CMBL + n*136 + 64 + mt*16 + q*4) = ll4;
  }
  f32x4 u1[4];
  #pragma unroll
  for (int mt = 0; mt < 4; ++mt) u1[mt] = *(const f32x4*)(g1_b + mt*16 + q*4);
  #pragma unroll
  for (int ks = 0; ks < 4; ++ks) {
    const half8 bh = *(const half8*)(wa + CMBH + n*136 + ks*32 + q*8);
    const half8 bl = *(const half8*)(wa + CMBL + n*136 + ks*32 + q*8);
    #pragma unroll
    for (int mt = 0; mt < 4; ++mt) {
      const half8 ah = *(const half8*)(sWF + G1H + (size_t)((mt*4 + ks)*64 + lane)*8);
      const half8 al = *(const half8*)(sWF + G1L + (size_t)((mt*4 + ks)*64 + lane)*8);
      u1[mt] = mfma16k32(al, bh, u1[mt]);
      u1[mt] = mfma16k32(ah, bl, u1[mt]);
      u1[mt] = mfma16k32(ah, bh, u1[mt]);
    }
  }
  #pragma unroll
  for (int mt = 0; mt < 4; ++mt) {
    half4 th4, tl4;
    #pragma unroll
    for (int r = 0; r < 4; ++r) {
      float e = __expf(2.f*u1[mt][r]);
      float t1 = 1.f - 2.f/(e + 1.f);
      _Float16 hi = (_Float16)t1;
      th4[r] = hi; tl4[r] = (_Float16)(t1 - (float)hi);
    }
    *(half4*)(wa + T1H + n*72 + mt*16 + q*4) = th4;
    *(half4*)(wa + T1L + n*72 + mt*16 + q*4) = tl4;
  }
  f32x4 u2[4];
  #pragma unroll
  for (int mt = 0; mt < 4; ++mt) u2[mt] = *(const f32x4*)(g2_b + mt*16 + q*4);
  #pragma unroll
  for (int ks = 0; ks < 2; ++ks) {
    const half8 bh = *(const half8*)(wa + T1H + n*72 + ks*32 + q*8);
    const half8 bl = *(const half8*)(wa + T1L + n*72 + ks*32 + q*8);
    #pragma unroll
    for (int mt = 0; mt < 4; ++mt) {
      const half8 ah = *(const half8*)(sWF + G2H + (size_t)((mt*2 + ks)*64 + lane)*8);
      const half8 al = *(const half8*)(sWF + G2L + (size_t)((mt*2 + ks)*64 + lane)*8);
      u2[mt] = mfma16k32(al, bh, u2[mt]);
      u2[mt] = mfma16k32(ah, bl, u2[mt]);
      u2[mt] = mfma16k32(ah, bh, u2[mt]);
    }
  }
  #pragma unroll
  for (int mt = 0; mt < 4; ++mt) {
    half4 fh4, fl4;
    #pragma unroll
    for (int r = 0; r < 4; ++r) {
      float gate = 1.f/(1.f + __expf(-u2[mt][r]));
      float f = sfv[mt][r] * gate;
      _Float16 hi = (_Float16)f;
      fh4[r] = hi; fl4[r] = (_Float16)(f - (float)hi);
    }
    *(half4*)(wa + FLH + n*72 + mt*16 + q*4) = fh4;
    *(half4*)(wa + FLL + n*72 + mt*16 + q*4) = fl4;
  }
  f32x4 u3[2];
  #pragma unroll
  for (int mt = 0; mt < 2; ++mt) u3[mt] = *(const f32x4*)(h1_b + mt*16 + q*4);
  #pragma unroll
  for (int ks = 0; ks < 2; ++ks) {
    const half8 bh = *(const half8*)(wa + FLH + n*72 + ks*32 + q*8);
    const half8 bl = *(const half8*)(wa + FLL + n*72 + ks*32 + q*8);
    #pragma unroll
    for (int mt = 0; mt < 2; ++mt) {
      const half8 ah = *(const half8*)(sWF + H1H + (size_t)((mt*2 + ks)*64 + lane)*8);
      const half8 al = *(const half8*)(sWF + H1L + (size_t)((mt*2 + ks)*64 + lane)*8);
      u3[mt] = mfma16k32(al, bh, u3[mt]);
      u3[mt] = mfma16k32(ah, bl, u3[mt]);
      u3[mt] = mfma16k32(ah, bh, u3[mt]);
    }
  }
  #pragma unroll
  for (int mt = 0; mt < 2; ++mt) {
    half4 rh4, rl4;
    #pragma unroll
    for (int r = 0; r < 4; ++r) {
      float v = fmaxf(u3[mt][r], 0.f);
      _Float16 hi = (_Float16)v;
      rh4[r] = hi; rl4[r] = (_Float16)(v - (float)hi);
    }
    *(half4*)(wa + RH + n*40 + mt*16 + q*4) = rh4;
    *(half4*)(wa + RL + n*40 + mt*16 + q*4) = rl4;
  }
  {
    f32x4 u4;
    if (q == 0) { u4[0] = h2_b[0]; u4[1] = h2_b[1]; u4[2] = h2_b[2]; u4[3] = 0.f; }
    else { u4[0] = 0.f; u4[1] = 0.f; u4[2] = 0.f; u4[3] = 0.f; }
    const half8 bh = *(const half8*)(wa + RH + n*40 + q*8);
    const half8 bl = *(const half8*)(wa + RL + n*40 + q*8);
    const half8 ah = *(const half8*)(sWF + H2H + (size_t)lane*8);
    const half8 al = *(const half8*)(sWF + H2L + (size_t)lane*8);
    u4 = mfma16k32(al, bh, u4);
    u4 = mfma16k32(ah, bl, u4);
    u4 = mfma16k32(ah, bh, u4);
    if (q == 0) {
      out[(size_t)(B0 + n)*3 + 0] = u4[0];
      out[(size_t)(B0 + n)*3 + 1] = u4[1];
      out[(size_t)(B0 + n)*3 + 2] = u4[2];
    }
  }
}

// ============================ launch ============================
extern "C" void kernel_launch(void* const* d_in, const int* in_sizes, int n_in,
                              void* d_out, int out_size, void* d_ws, size_t ws_size,
                              hipStream_t stream) {
  const float* x       = (const float*)d_in[0];
  const float* conv1_w = (const float*)d_in[1];
  const float* conv1_b = (const float*)d_in[2];
  const float* conv2_w = (const float*)d_in[3];
  const float* conv2_b = (const float*)d_in[4];
  const float* conv3_w = (const float*)d_in[5];
  const float* conv3_b = (const float*)d_in[6];
  const float* bn1_g   = (const float*)d_in[7];
  const float* bn1_b   = (const float*)d_in[8];
  const float* bn2_g   = (const float*)d_in[9];
  const float* bn2_b   = (const float*)d_in[10];
  const float* bn3_g   = (const float*)d_in[11];
  const float* bn3_b   = (const float*)d_in[12];
  const float* proj_w  = (const float*)d_in[13];
  const float* proj_b  = (const float*)d_in[14];
  const float* A       = (const float*)d_in[15];
  const float* Bm      = (const float*)d_in[16];
  const float* Cm      = (const float*)d_in[17];
  const float* out_w   = (const float*)d_in[18];
  const float* out_b   = (const float*)d_in[19];
  const float* g1_w    = (const float*)d_in[20];
  const float* g1_b    = (const float*)d_in[21];
  const float* g2_w    = (const float*)d_in[22];
  const float* g2_b    = (const float*)d_in[23];
  const float* h1_w    = (const float*)d_in[24];
  const float* h1_b    = (const float*)d_in[25];
  const float* h2_w    = (const float*)d_in[26];
  const float* h2_b    = (const float*)d_in[27];
  float* ws = (float*)d_ws;
  float* out = (float*)d_out;

  prep_kernel<<<64, 256, 0, stream>>>(conv1_w, conv1_b, conv2_w, conv2_b,
      conv3_w, conv3_b, bn1_g, bn1_b, bn2_g, bn2_b, bn3_g, bn3_b,
      proj_w, proj_b, A, Bm, Cm, out_w, g1_w, g2_w, h1_w, h2_w, ws);

  conv123_kernel<<<NRNN + NB/16, 256, 0, stream>>>(x, ws, A, ws + OFF_H,
      ws + OFF_SF);

  tail_kernel<<<NB/64, 256, 0, stream>>>(ws, g1_b, g2_b, h1_b, h2_b, out_b, out);
}